// Round 7
// baseline (349.343 us; speedup 1.0000x reference)
//
#include <hip/hip_runtime.h>
#include <math.h>

#define DIM 768
#define HEADS 12
#define DHEAD 64
#define NTOK 31
#define BATCH 512
#define MTOK (BATCH * NTOK)   /* 15872 */
#define HIDDEN 3072
#define QKVN 2304
#define MASK_VAL -987654321.0f

typedef short s16x8 __attribute__((ext_vector_type(8)));
typedef float f32x4 __attribute__((ext_vector_type(4)));

static __device__ __forceinline__ float bs2f(unsigned short u) {
  unsigned int x = ((unsigned int)u) << 16;
  return __builtin_bit_cast(float, x);
}
static __device__ __forceinline__ unsigned short f2bs(float f) {
  unsigned int x = __builtin_bit_cast(unsigned int, f);
  x += 0x7fffu + ((x >> 16) & 1u);
  return (unsigned short)(x >> 16);
}

// async global->LDS, 16B per lane, wave-uniform LDS base + lane*16
static __device__ __forceinline__ void gload16(const unsigned short* g, unsigned short* l) {
  __builtin_amdgcn_global_load_lds(
      (const __attribute__((address_space(1))) unsigned int*)g,
      (__attribute__((address_space(3))) unsigned int*)l, 16, 0, 0);
}

// ---------------- weight transpose: w[K][N] f32 -> wt[N][K] bf16 ----------------
__global__ __launch_bounds__(256) void transpose_kernel(const float* __restrict__ w,
                                                        unsigned short* __restrict__ wt,
                                                        int K, int N) {
  __shared__ float t[64][65];
  int k0 = blockIdx.y * 64, n0 = blockIdx.x * 64;
  int tid = threadIdx.x;
  int r = tid >> 4, c4 = (tid & 15) * 4;
#pragma unroll
  for (int i = 0; i < 4; ++i) {
    float4 v = *(const float4*)(w + (size_t)(k0 + r + i * 16) * N + n0 + c4);
    t[r + i * 16][c4] = v.x;
    t[r + i * 16][c4 + 1] = v.y;
    t[r + i * 16][c4 + 2] = v.z;
    t[r + i * 16][c4 + 3] = v.w;
  }
  __syncthreads();
#pragma unroll
  for (int i = 0; i < 4; ++i) {
    int n = r + i * 16;
    ushort4 o;
    o.x = f2bs(t[c4 + 0][n]);
    o.y = f2bs(t[c4 + 1][n]);
    o.z = f2bs(t[c4 + 2][n]);
    o.w = f2bs(t[c4 + 3][n]);
    *(ushort4*)(wt + (size_t)(n0 + n) * K + k0 + c4) = o;
  }
}

// ---------------- LayerNorm (f32 in): one wave per token row ----------------
__global__ __launch_bounds__(256) void ln_kernel(const float* __restrict__ x,
                                                 const float* __restrict__ g,
                                                 const float* __restrict__ bta,
                                                 unsigned short* __restrict__ out) {
  int wid = threadIdx.x >> 6, lane = threadIdx.x & 63;
  size_t row = (size_t)blockIdx.x * 4 + wid;
  const float4* xr = (const float4*)(x + row * DIM);
  float4 v[3];
  v[0] = xr[lane];
  v[1] = xr[lane + 64];
  v[2] = xr[lane + 128];
  float s = 0.f, sq = 0.f;
#pragma unroll
  for (int i = 0; i < 3; ++i) {
    s += v[i].x + v[i].y + v[i].z + v[i].w;
    sq += v[i].x * v[i].x + v[i].y * v[i].y + v[i].z * v[i].z + v[i].w * v[i].w;
  }
#pragma unroll
  for (int off = 32; off; off >>= 1) {
    s += __shfl_xor(s, off);
    sq += __shfl_xor(sq, off);
  }
  float mu = s * (1.f / DIM);
  float var = sq * (1.f / DIM) - mu * mu;
  float rs = rsqrtf(var + 1e-5f);
#pragma unroll
  for (int i = 0; i < 3; ++i) {
    int col = i * 256 + lane * 4;
    float4 gg = *(const float4*)(g + col);
    float4 bb = *(const float4*)(bta + col);
    ushort4 o;
    o.x = f2bs((v[i].x - mu) * rs * gg.x + bb.x);
    o.y = f2bs((v[i].y - mu) * rs * gg.y + bb.y);
    o.z = f2bs((v[i].z - mu) * rs * gg.z + bb.z);
    o.w = f2bs((v[i].w - mu) * rs * gg.w + bb.w);
    *(ushort4*)(out + row * DIM + col) = o;
  }
}

// ---------------- LayerNorm (bf16 in): one wave per token row ----------------
__global__ __launch_bounds__(256) void ln_bf16_kernel(const unsigned short* __restrict__ x,
                                                      const float* __restrict__ g,
                                                      const float* __restrict__ bta,
                                                      unsigned short* __restrict__ out) {
  int wid = threadIdx.x >> 6, lane = threadIdx.x & 63;
  size_t row = (size_t)blockIdx.x * 4 + wid;
  const unsigned short* xr = x + row * DIM;
  float v[12];
#pragma unroll
  for (int i = 0; i < 3; ++i) {
    ushort4 u = *(const ushort4*)(xr + i * 256 + lane * 4);
    v[i * 4 + 0] = bs2f(u.x);
    v[i * 4 + 1] = bs2f(u.y);
    v[i * 4 + 2] = bs2f(u.z);
    v[i * 4 + 3] = bs2f(u.w);
  }
  float s = 0.f, sq = 0.f;
#pragma unroll
  for (int i = 0; i < 12; ++i) {
    s += v[i];
    sq += v[i] * v[i];
  }
#pragma unroll
  for (int off = 32; off; off >>= 1) {
    s += __shfl_xor(s, off);
    sq += __shfl_xor(sq, off);
  }
  float mu = s * (1.f / DIM);
  float var = sq * (1.f / DIM) - mu * mu;
  float rs = rsqrtf(var + 1e-5f);
#pragma unroll
  for (int i = 0; i < 3; ++i) {
    int col = i * 256 + lane * 4;
    float4 gg = *(const float4*)(g + col);
    float4 bb = *(const float4*)(bta + col);
    ushort4 o;
    o.x = f2bs((v[i * 4 + 0] - mu) * rs * gg.x + bb.x);
    o.y = f2bs((v[i * 4 + 1] - mu) * rs * gg.y + bb.y);
    o.z = f2bs((v[i * 4 + 2] - mu) * rs * gg.z + bb.z);
    o.w = f2bs((v[i * 4 + 3] - mu) * rs * gg.w + bb.w);
    *(ushort4*)(out + row * DIM + col) = o;
  }
}

// ================= 8-phase 256x256 GEMM (m201 template form) =================
// C[M,N] = A[M,K](bf16,k-major) @ Bt[N,K](bf16,k-major)^T
// 512 thr = 8 waves (2M x 4N), per-wave C = 128x64, BK=64 (2 khalves of 32).
// LDS 128KB: [buf(2)][mat A=0/B=1][kh(2)][256 rows][32 cols] bf16, 64B rows.
// Read swizzle: byte ^= ((row>>1)&3)<<4 ; staged via inverse-swizzled global src.
// EPI: 0 = bf16 raw; 2 = +bias, tanh-GELU -> bf16; 3 = +bias +f32 resid -> bf16;
//      4 = +bias +bf16 resid -> f32

template <int BUF, int MH, int KH, int VM, typename STF>
__device__ __forceinline__ void gphase(const char* aP0, const char* aP1,
                                       const char* bP0, const char* bP1,
                                       s16x8* bk, f32x4 (&acc)[8][4], STF&& stage) {
  const char* aP = BUF ? aP1 : aP0;
  const char* bP = BUF ? bP1 : bP0;
  s16x8 af[4];
  if (MH == 0) {
#pragma unroll
    for (int ni = 0; ni < 4; ++ni)
      bk[ni] = *(const s16x8*)(bP + KH * 16384 + ni * 1024);
  }
#pragma unroll
  for (int mi = 0; mi < 4; ++mi)
    af[mi] = *(const s16x8*)(aP + KH * 16384 + MH * 4096 + mi * 1024);
  stage();
  if (VM == 6) asm volatile("s_waitcnt vmcnt(6)");
  if (VM == 0) asm volatile("s_waitcnt vmcnt(0)");
  __builtin_amdgcn_s_barrier();
  asm volatile("s_waitcnt lgkmcnt(0)");
  __builtin_amdgcn_s_setprio(1);
#pragma unroll
  for (int mi = 0; mi < 4; ++mi)
#pragma unroll
    for (int ni = 0; ni < 4; ++ni)
      acc[MH * 4 + mi][ni] =
          __builtin_amdgcn_mfma_f32_16x16x32_bf16(af[mi], bk[ni], acc[MH * 4 + mi][ni], 0, 0, 0);
  __builtin_amdgcn_s_setprio(0);
  __builtin_amdgcn_s_barrier();
}

template <int EPI>
__global__ __launch_bounds__(512, 2) void gemm8_kernel(
    const unsigned short* __restrict__ A, const unsigned short* __restrict__ Bt,
    void* __restrict__ outp, const float* __restrict__ bias,
    const void* __restrict__ resid, int M, int N, int K, int ntn) {
  __shared__ unsigned short lds[65536];  // 128 KiB
  const char* ldsb = (const char*)lds;
  int tid = threadIdx.x;
  int lane = tid & 63, w = tid >> 6;
  int wm = w >> 2, wn = w & 3;
  int fr = lane & 15, q = lane >> 4;

  // bijective XCD swizzle (m204)
  int nwg = gridDim.x, orig = blockIdx.x;
  int qd = nwg >> 3, r8 = nwg & 7, xcd = orig & 7, loc = orig >> 3;
  int bid = (xcd < r8 ? xcd * (qd + 1) : r8 * (qd + 1) + (xcd - r8) * qd) + loc;
  int m0 = (bid / ntn) * 256, n0 = (bid % ntn) * 256;

  // frag-read base pointers (per-lane constant; per-phase deltas are imm offsets)
  int rdoff = (q * 16) ^ (((fr >> 1) & 3) << 4);
  const char* aP0 = ldsb + (wm * 128 + fr) * 64 + rdoff;
  const char* aP1 = aP0 + 65536;
  const char* bP0 = ldsb + 32768 + (wn * 64 + fr) * 64 + rdoff;
  const char* bP1 = bP0 + 65536;

  // stage addressing: thread covers dest rows {srow, srow+128}, 16B each
  int srow = tid >> 2;
  int seoff = (((tid & 3) ^ ((srow >> 1) & 3))) << 3;  // inverse-swizzled elem off
  const char* Ab = (const char*)A + ((size_t)(m0 + srow) * K + seoff) * 2;
  const char* Bb = (const char*)Bt + ((size_t)(n0 + srow) * K + seoff) * 2;
  size_t rstep = (size_t)K * 256;  // 128 rows

  auto stg = [&](int mat, int kh, int buf, int tile) {
    const char* gp = (mat ? Bb : Ab) + tile * 128 + kh * 64;
    unsigned short* lp = lds + buf * 32768 + mat * 16384 + kh * 8192 + w * 512;
    gload16((const unsigned short*)gp, lp);
    gload16((const unsigned short*)(gp + rstep), lp + 4096);
  };
  auto nop = [&] {};

  f32x4 acc[8][4] = {};
  s16x8 bk[4];
  int NT = K / 64;

  // prologue: t0 fully + t1 {Bk0, Ak0, Bk1}; force t0 complete
  stg(1, 0, 0, 0);
  stg(0, 0, 0, 0);
  stg(1, 1, 0, 0);
  stg(0, 1, 0, 0);
  stg(1, 0, 1, 1);
  stg(0, 0, 1, 1);
  stg(1, 1, 1, 1);
  asm volatile("s_waitcnt vmcnt(6)");
  __builtin_amdgcn_s_barrier();

  for (int t = 0; t + 3 < NT; t += 2) {
    gphase<0, 0, 0, -1>(aP0, aP1, bP0, bP1, bk, acc, [&] { stg(0, 1, 1, t + 1); });
    gphase<0, 1, 0, -1>(aP0, aP1, bP0, bP1, bk, acc, [&] { stg(1, 0, 0, t + 2); });
    gphase<0, 0, 1, -1>(aP0, aP1, bP0, bP1, bk, acc, [&] { stg(0, 0, 0, t + 2); });
    gphase<0, 1, 1, 6>(aP0, aP1, bP0, bP1, bk, acc, [&] { stg(1, 1, 0, t + 2); });
    gphase<1, 0, 0, -1>(aP0, aP1, bP0, bP1, bk, acc, [&] { stg(0, 1, 0, t + 2); });
    gphase<1, 1, 0, -1>(aP0, aP1, bP0, bP1, bk, acc, [&] { stg(1, 0, 1, t + 3); });
    gphase<1, 0, 1, -1>(aP0, aP1, bP0, bP1, bk, acc, [&] { stg(0, 0, 1, t + 3); });
    gphase<1, 1, 1, 6>(aP0, aP1, bP0, bP1, bk, acc, [&] { stg(1, 1, 1, t + 3); });
  }
  // epilogue iteration: compute {NT-2, NT-1}
  gphase<0, 0, 0, -1>(aP0, aP1, bP0, bP1, bk, acc, [&] { stg(0, 1, 1, NT - 1); });
  gphase<0, 1, 0, -1>(aP0, aP1, bP0, bP1, bk, acc, nop);
  gphase<0, 0, 1, -1>(aP0, aP1, bP0, bP1, bk, acc, nop);
  gphase<0, 1, 1, 0>(aP0, aP1, bP0, bP1, bk, acc, nop);
  gphase<1, 0, 0, -1>(aP0, aP1, bP0, bP1, bk, acc, nop);
  gphase<1, 1, 0, -1>(aP0, aP1, bP0, bP1, bk, acc, nop);
  gphase<1, 0, 1, -1>(aP0, aP1, bP0, bP1, bk, acc, nop);
  gphase<1, 1, 1, -1>(aP0, aP1, bP0, bP1, bk, acc, nop);

  // C write: row = m0 + wm*128 + am*16 + q*4 + rr, col = n0 + wn*64 + ni*16 + fr
#pragma unroll
  for (int am = 0; am < 8; ++am) {
#pragma unroll
    for (int ni = 0; ni < 4; ++ni) {
#pragma unroll
      for (int rr = 0; rr < 4; ++rr) {
        int row = m0 + wm * 128 + am * 16 + q * 4 + rr;
        int col = n0 + wn * 64 + ni * 16 + fr;
        size_t idx = (size_t)row * N + col;
        float v = acc[am][ni][rr];
        if (EPI == 0) {
          ((unsigned short*)outp)[idx] = f2bs(v);
        } else if (EPI == 2) {
          float t = v + bias[col];
          float arg = 1.5957691216f * t * (1.f + 0.044715f * t * t);
          float gl = t * __builtin_amdgcn_rcpf(1.f + __expf(-arg));
          ((unsigned short*)outp)[idx] = f2bs(gl);
        } else if (EPI == 3) {
          float t = v + bias[col] + ((const float*)resid)[idx];
          ((unsigned short*)outp)[idx] = f2bs(t);
        } else {
          float t = v + bias[col] + bs2f(((const unsigned short*)resid)[idx]);
          ((float*)outp)[idx] = t;
        }
      }
    }
  }
}

// ---------------- MFMA attention: one wave per (batch, head) ----------------
__global__ __launch_bounds__(256) void attn_mfma_kernel(const unsigned short* __restrict__ qkv,
                                                        const float* __restrict__ scale,
                                                        unsigned short* __restrict__ ao) {
  __shared__ unsigned short Vt[4][64][40];  // 20480 B
  __shared__ unsigned short Pl[4][32][32];  // 8192 B
  int wid = threadIdx.x >> 6, lane = threadIdx.x & 63;
  int pair = blockIdx.x * 4 + wid;
  int b = pair / HEADS, h = pair % HEADS;
  const unsigned short* base = qkv + (size_t)b * NTOK * QKVN + h * DHEAD;
  const unsigned short* Qp = base;
  const unsigned short* Kp = base + 768;
  const unsigned short* Vp = base + 1536;

  int c = lane & 15, q = lane >> 4;
  int oct = q * 8;

  // ---- stage V transposed: lane owns V^T row d=lane ----
  unsigned short vcol[NTOK];
#pragma unroll
  for (int j = 0; j < NTOK; ++j) vcol[j] = Vp[(size_t)j * QKVN + lane];
#pragma unroll
  for (int j = 0; j < NTOK; ++j) Vt[wid][lane][j] = vcol[j];
  Vt[wid][lane][31] = 0;  // padded key column

  // ---- load Q,K fragments (rows >= 31 zeroed) ----
  s16x8 kf[2][2] = {{{0}}}, qf[2][2] = {{{0}}};
#pragma unroll
  for (int t = 0; t < 2; ++t) {
    int row = t * 16 + c;
    if (row < NTOK) {
#pragma unroll
      for (int s = 0; s < 2; ++s) {
        kf[t][s] = *(const s16x8*)(Kp + (size_t)row * QKVN + s * 32 + oct);
        qf[t][s] = *(const s16x8*)(Qp + (size_t)row * QKVN + s * 32 + oct);
      }
    }
  }

  // ---- S^T = K·Q^T ----
  f32x4 st[2][2] = {};
#pragma unroll
  for (int jt = 0; jt < 2; ++jt)
#pragma unroll
    for (int it = 0; it < 2; ++it)
#pragma unroll
      for (int s = 0; s < 2; ++s)
        st[jt][it] =
            __builtin_amdgcn_mfma_f32_16x16x32_bf16(kf[jt][s], qf[it][s], st[jt][it], 0, 0, 0);

  float scl = scale[h];
  // scale + diagonal/pad mask; value (jt,it,r): j=jt*16+4q+r, i=it*16+c
  float p[2][2][4];
#pragma unroll
  for (int it = 0; it < 2; ++it)
#pragma unroll
    for (int jt = 0; jt < 2; ++jt)
#pragma unroll
      for (int r = 0; r < 4; ++r) {
        int j = jt * 16 + 4 * q + r;
        int i = it * 16 + c;
        float v = st[jt][it][r] * scl;
        if (j == 31 || j == i) v = MASK_VAL;
        p[it][jt][r] = v;
      }
  // softmax per column i (4 lanes hold a column: xor16, xor32)
#pragma unroll
  for (int it = 0; it < 2; ++it) {
    float m = p[it][0][0];
#pragma unroll
    for (int jt = 0; jt < 2; ++jt)
#pragma unroll
      for (int r = 0; r < 4; ++r) m = fmaxf(m, p[it][jt][r]);
    m = fmaxf(m, __shfl_xor(m, 16));
    m = fmaxf(m, __shfl_xor(m, 32));
    float s = 0.f;
#pragma unroll
    for (int jt = 0; jt < 2; ++jt)
#pragma unroll
      for (int r = 0; r < 4; ++r) {
        float e = __expf(p[it][jt][r] - m);
        p[it][jt][r] = e;
        s += e;
      }
    s += __shfl_xor(s, 16);
    s += __shfl_xor(s, 32);
    float inv = __builtin_amdgcn_rcpf(s);
#pragma unroll
    for (int jt = 0; jt < 2; ++jt)
#pragma unroll
      for (int r = 0; r < 4; ++r) p[it][jt][r] *= inv;
  }
  // P -> LDS [i][j] (rows i, j-contiguous quads)
#pragma unroll
  for (int it = 0; it < 2; ++it)
#pragma unroll
    for (int jt = 0; jt < 2; ++jt) {
      unsigned int w0 =
          (unsigned int)f2bs(p[it][jt][0]) | ((unsigned int)f2bs(p[it][jt][1]) << 16);
      unsigned int w1 =
          (unsigned int)f2bs(p[it][jt][2]) | ((unsigned int)f2bs(p[it][jt][3]) << 16);
      uint2 pk = {w0, w1};
      *(uint2*)&Pl[wid][it * 16 + c][jt * 16 + 4 * q] = pk;
    }

  // ---- O = P·V ----
  s16x8 pa[2];
#pragma unroll
  for (int it = 0; it < 2; ++it) pa[it] = *(const s16x8*)&Pl[wid][it * 16 + c][oct];
  f32x4 o[2][4];
#pragma unroll
  for (int it = 0; it < 2; ++it)
#pragma unroll
    for (int dt = 0; dt < 4; ++dt) {
      s16x8 vb = *(const s16x8*)&Vt[wid][dt * 16 + c][oct];
      f32x4 z = {0.f, 0.f, 0.f, 0.f};
      o[it][dt] = __builtin_amdgcn_mfma_f32_16x16x32_bf16(pa[it], vb, z, 0, 0, 0);
    }
  // store: row i = it*16+4q+r (skip i==31), col d = dt*16+c
#pragma unroll
  for (int it = 0; it < 2; ++it)
#pragma unroll
    for (int r = 0; r < 4; ++r) {
      int i = it * 16 + 4 * q + r;
      if (i < NTOK) {
        size_t rowoff = ((size_t)b * NTOK + i) * DIM + h * DHEAD;
#pragma unroll
        for (int dt = 0; dt < 4; ++dt) ao[rowoff + dt * 16 + c] = f2bs(o[it][dt][r]);
      }
    }
}

// ---------------- launcher ----------------
// Workspace (peak 209,190,912 B < 256 MiB):
//   buf1 @ 0          (24,379,392): h -> ao -> h2
//   qkv/x2 @ 24,379,392 (73,138,176): qkv bf16, then x2 bf16 (qkv dead)
//   g    @ 97,517,568 (97,517,568): MLP hidden bf16
//   wT   @ 195,035,136 (14,155,776): pre-transposed bf16 weights
extern "C" void kernel_launch(void* const* d_in, const int* in_sizes, int n_in,
                              void* d_out, int out_size, void* d_ws, size_t ws_size,
                              hipStream_t stream) {
  (void)in_sizes; (void)n_in; (void)out_size; (void)ws_size;
  const float* x = (const float*)d_in[0];
  const float* ln1_g = (const float*)d_in[1];
  const float* ln1_b = (const float*)d_in[2];
  const float* w_qkv = (const float*)d_in[3];
  const float* scale = (const float*)d_in[4];
  const float* w_o = (const float*)d_in[5];
  const float* b_o = (const float*)d_in[6];
  const float* ln2_g = (const float*)d_in[7];
  const float* ln2_b = (const float*)d_in[8];
  const float* w1 = (const float*)d_in[9];
  const float* b1 = (const float*)d_in[10];
  const float* w2 = (const float*)d_in[11];
  const float* b2 = (const float*)d_in[12];

  char* ws = (char*)d_ws;
  unsigned short* buf1 = (unsigned short*)(ws + 0);
  unsigned short* qkv_bf = (unsigned short*)(ws + 24379392);
  unsigned short* x2 = (unsigned short*)(ws + 24379392);  // aliases qkv (qkv dead)
  unsigned short* g_bf = (unsigned short*)(ws + 97517568);
  unsigned short* wqkvT = (unsigned short*)(ws + 195035136);  // [2304][768]
  unsigned short* woT = (unsigned short*)(ws + 198574080);    // [768][768]
  unsigned short* w1T = (unsigned short*)(ws + 199753728);    // [3072][768]
  unsigned short* w2T = (unsigned short*)(ws + 204472320);    // [768][3072]

  transpose_kernel<<<dim3(QKVN / 64, DIM / 64), 256, 0, stream>>>(w_qkv, wqkvT, DIM, QKVN);
  transpose_kernel<<<dim3(DIM / 64, DIM / 64), 256, 0, stream>>>(w_o, woT, DIM, DIM);
  transpose_kernel<<<dim3(HIDDEN / 64, DIM / 64), 256, 0, stream>>>(w1, w1T, DIM, HIDDEN);
  transpose_kernel<<<dim3(DIM / 64, HIDDEN / 64), 256, 0, stream>>>(w2, w2T, HIDDEN, DIM);

  ln_kernel<<<MTOK / 4, 256, 0, stream>>>(x, ln1_g, ln1_b, buf1);
  gemm8_kernel<0><<<(MTOK / 256) * (QKVN / 256), 512, 0, stream>>>(
      buf1, wqkvT, qkv_bf, nullptr, nullptr, MTOK, QKVN, DIM, QKVN / 256);
  attn_mfma_kernel<<<(BATCH * HEADS) / 4, 256, 0, stream>>>(qkv_bf, scale, buf1);
  // proj + residual(x, f32) -> x2 (bf16)
  gemm8_kernel<3><<<(MTOK / 256) * (DIM / 256), 512, 0, stream>>>(
      buf1, woT, x2, b_o, x, MTOK, DIM, DIM, DIM / 256);
  ln_bf16_kernel<<<MTOK / 4, 256, 0, stream>>>(x2, ln2_g, ln2_b, buf1);
  // mlp1 + tanh-GELU
  gemm8_kernel<2><<<(MTOK / 256) * (HIDDEN / 256), 512, 0, stream>>>(
      buf1, w1T, g_bf, b1, nullptr, MTOK, HIDDEN, DIM, HIDDEN / 256);
  // mlp2 + residual(x2, bf16) -> out (f32)
  gemm8_kernel<4><<<(MTOK / 256) * (DIM / 256), 512, 0, stream>>>(
      g_bf, w2T, (float*)d_out, b2, x2, MTOK, DIM, HIDDEN, DIM / 256);
}

// Round 8
// 342.267 us; speedup vs baseline: 1.0207x; 1.0207x over previous
//
#include <hip/hip_runtime.h>
#include <math.h>

#define DIM 768
#define HEADS 12
#define DHEAD 64
#define NTOK 31
#define BATCH 512
#define MTOK (BATCH * NTOK)   /* 15872 */
#define HIDDEN 3072
#define QKVN 2304
#define MASK_VAL -987654321.0f

typedef short s16x8 __attribute__((ext_vector_type(8)));
typedef float f32x4 __attribute__((ext_vector_type(4)));

static __device__ __forceinline__ float bs2f(unsigned short u) {
  unsigned int x = ((unsigned int)u) << 16;
  return __builtin_bit_cast(float, x);
}
static __device__ __forceinline__ unsigned short f2bs(float f) {
  unsigned int x = __builtin_bit_cast(unsigned int, f);
  x += 0x7fffu + ((x >> 16) & 1u);
  return (unsigned short)(x >> 16);
}

// async global->LDS, 16B per lane, wave-uniform LDS base + lane*16
static __device__ __forceinline__ void gload16(const unsigned short* g, unsigned short* l) {
  __builtin_amdgcn_global_load_lds(
      (const __attribute__((address_space(1))) unsigned int*)g,
      (__attribute__((address_space(3))) unsigned int*)l, 16, 0, 0);
}

// ---------------- weight transpose: w[K][N] f32 -> wt[N][K] bf16 ----------------
__global__ __launch_bounds__(256) void transpose_kernel(const float* __restrict__ w,
                                                        unsigned short* __restrict__ wt,
                                                        int K, int N) {
  __shared__ float t[64][65];
  int k0 = blockIdx.y * 64, n0 = blockIdx.x * 64;
  int tid = threadIdx.x;
  int r = tid >> 4, c4 = (tid & 15) * 4;
#pragma unroll
  for (int i = 0; i < 4; ++i) {
    float4 v = *(const float4*)(w + (size_t)(k0 + r + i * 16) * N + n0 + c4);
    t[r + i * 16][c4] = v.x;
    t[r + i * 16][c4 + 1] = v.y;
    t[r + i * 16][c4 + 2] = v.z;
    t[r + i * 16][c4 + 3] = v.w;
  }
  __syncthreads();
#pragma unroll
  for (int i = 0; i < 4; ++i) {
    int n = r + i * 16;
    ushort4 o;
    o.x = f2bs(t[c4 + 0][n]);
    o.y = f2bs(t[c4 + 1][n]);
    o.z = f2bs(t[c4 + 2][n]);
    o.w = f2bs(t[c4 + 3][n]);
    *(ushort4*)(wt + (size_t)(n0 + n) * K + k0 + c4) = o;
  }
}

// ---------------- LayerNorm (f32 in): one wave per token row ----------------
__global__ __launch_bounds__(256) void ln_kernel(const float* __restrict__ x,
                                                 const float* __restrict__ g,
                                                 const float* __restrict__ bta,
                                                 unsigned short* __restrict__ out) {
  int wid = threadIdx.x >> 6, lane = threadIdx.x & 63;
  size_t row = (size_t)blockIdx.x * 4 + wid;
  const float4* xr = (const float4*)(x + row * DIM);
  float4 v[3];
  v[0] = xr[lane];
  v[1] = xr[lane + 64];
  v[2] = xr[lane + 128];
  float s = 0.f, sq = 0.f;
#pragma unroll
  for (int i = 0; i < 3; ++i) {
    s += v[i].x + v[i].y + v[i].z + v[i].w;
    sq += v[i].x * v[i].x + v[i].y * v[i].y + v[i].z * v[i].z + v[i].w * v[i].w;
  }
#pragma unroll
  for (int off = 32; off; off >>= 1) {
    s += __shfl_xor(s, off);
    sq += __shfl_xor(sq, off);
  }
  float mu = s * (1.f / DIM);
  float var = sq * (1.f / DIM) - mu * mu;
  float rs = rsqrtf(var + 1e-5f);
#pragma unroll
  for (int i = 0; i < 3; ++i) {
    int col = i * 256 + lane * 4;
    float4 gg = *(const float4*)(g + col);
    float4 bb = *(const float4*)(bta + col);
    ushort4 o;
    o.x = f2bs((v[i].x - mu) * rs * gg.x + bb.x);
    o.y = f2bs((v[i].y - mu) * rs * gg.y + bb.y);
    o.z = f2bs((v[i].z - mu) * rs * gg.z + bb.z);
    o.w = f2bs((v[i].w - mu) * rs * gg.w + bb.w);
    *(ushort4*)(out + row * DIM + col) = o;
  }
}

// ---------------- LayerNorm (bf16 in): one wave per token row ----------------
__global__ __launch_bounds__(256) void ln_bf16_kernel(const unsigned short* __restrict__ x,
                                                      const float* __restrict__ g,
                                                      const float* __restrict__ bta,
                                                      unsigned short* __restrict__ out) {
  int wid = threadIdx.x >> 6, lane = threadIdx.x & 63;
  size_t row = (size_t)blockIdx.x * 4 + wid;
  const unsigned short* xr = x + row * DIM;
  float v[12];
#pragma unroll
  for (int i = 0; i < 3; ++i) {
    ushort4 u = *(const ushort4*)(xr + i * 256 + lane * 4);
    v[i * 4 + 0] = bs2f(u.x);
    v[i * 4 + 1] = bs2f(u.y);
    v[i * 4 + 2] = bs2f(u.z);
    v[i * 4 + 3] = bs2f(u.w);
  }
  float s = 0.f, sq = 0.f;
#pragma unroll
  for (int i = 0; i < 12; ++i) {
    s += v[i];
    sq += v[i] * v[i];
  }
#pragma unroll
  for (int off = 32; off; off >>= 1) {
    s += __shfl_xor(s, off);
    sq += __shfl_xor(sq, off);
  }
  float mu = s * (1.f / DIM);
  float var = sq * (1.f / DIM) - mu * mu;
  float rs = rsqrtf(var + 1e-5f);
#pragma unroll
  for (int i = 0; i < 3; ++i) {
    int col = i * 256 + lane * 4;
    float4 gg = *(const float4*)(g + col);
    float4 bb = *(const float4*)(bta + col);
    ushort4 o;
    o.x = f2bs((v[i * 4 + 0] - mu) * rs * gg.x + bb.x);
    o.y = f2bs((v[i * 4 + 1] - mu) * rs * gg.y + bb.y);
    o.z = f2bs((v[i * 4 + 2] - mu) * rs * gg.z + bb.z);
    o.w = f2bs((v[i * 4 + 3] - mu) * rs * gg.w + bb.w);
    *(ushort4*)(out + row * DIM + col) = o;
  }
}

// ================= 8-phase 256x256 GEMM =================
// Minimal-wait ledger (loads, 2 per stg; queue order per 8-phase iter computing
// tiles t,t+1):  carried {t+1:B0,A0,B1}=6; issue ph1:t+1A1, ph2:t+2B0, ph3:t+2A0,
// ph4:t+2B1, ph5:t+2A1, ph6:t+3B0, ph7:t+3A0, ph8:t+3B1.
// Reads confirm-before-use: ph5 needs t+1{B0,A0} -> wait@ph4 vmcnt(10);
// ph7 needs t+1{B1,A1} -> wait@ph6 vmcnt(10); ph1' needs t+2{B0,A0} ->
// wait@ph8 vmcnt(10); ph3' needs t+2{B1,A1} -> wait@ph2' vmcnt(10).
// Every wait covers loads issued 5 phases earlier (was 3). Epilogue: ph4
// vmcnt(4) (t+1 B0,A0 of 8 outstanding), ph6 vmcnt(0).
// VM: -1 none, else exact vmcnt count.

template <int BUF, int MH, int KH, int VM, typename STF>
__device__ __forceinline__ void gphase(const char* aP0, const char* aP1,
                                       const char* bP0, const char* bP1,
                                       s16x8* bk, f32x4 (&acc)[8][4], STF&& stage) {
  const char* aP = BUF ? aP1 : aP0;
  const char* bP = BUF ? bP1 : bP0;
  s16x8 af[4];
  if (MH == 0) {
#pragma unroll
    for (int ni = 0; ni < 4; ++ni)
      bk[ni] = *(const s16x8*)(bP + KH * 16384 + ni * 1024);
  }
#pragma unroll
  for (int mi = 0; mi < 4; ++mi)
    af[mi] = *(const s16x8*)(aP + KH * 16384 + MH * 4096 + mi * 1024);
  stage();
  if (VM == 10) asm volatile("s_waitcnt vmcnt(10)");
  if (VM == 4) asm volatile("s_waitcnt vmcnt(4)");
  if (VM == 0) asm volatile("s_waitcnt vmcnt(0)");
  __builtin_amdgcn_s_barrier();
  asm volatile("s_waitcnt lgkmcnt(0)");
  __builtin_amdgcn_s_setprio(1);
#pragma unroll
  for (int mi = 0; mi < 4; ++mi)
#pragma unroll
    for (int ni = 0; ni < 4; ++ni)
      acc[MH * 4 + mi][ni] =
          __builtin_amdgcn_mfma_f32_16x16x32_bf16(af[mi], bk[ni], acc[MH * 4 + mi][ni], 0, 0, 0);
  __builtin_amdgcn_s_setprio(0);
  __builtin_amdgcn_s_barrier();
}

template <int EPI>
__device__ __forceinline__ void gemm8_body(
    const unsigned short* __restrict__ A, const unsigned short* __restrict__ Bt,
    void* __restrict__ outp, const float* __restrict__ bias,
    const void* __restrict__ resid, int M, int N, int K, int ntn) {
  __shared__ unsigned short lds[65536];  // 128 KiB
  const char* ldsb = (const char*)lds;
  int tid = threadIdx.x;
  int lane = tid & 63, w = tid >> 6;
  int wm = w >> 2, wn = w & 3;
  int fr = lane & 15, q = lane >> 4;

  // bijective XCD swizzle (m204)
  int nwg = gridDim.x, orig = blockIdx.x;
  int qd = nwg >> 3, r8 = nwg & 7, xcd = orig & 7, loc = orig >> 3;
  int bid = (xcd < r8 ? xcd * (qd + 1) : r8 * (qd + 1) + (xcd - r8) * qd) + loc;
  int m0 = (bid / ntn) * 256, n0 = (bid % ntn) * 256;

  // frag-read base pointers (per-lane constant; per-phase deltas are imm offsets)
  int rdoff = (q * 16) ^ (((fr >> 1) & 3) << 4);
  const char* aP0 = ldsb + (wm * 128 + fr) * 64 + rdoff;
  const char* aP1 = aP0 + 65536;
  const char* bP0 = ldsb + 32768 + (wn * 64 + fr) * 64 + rdoff;
  const char* bP1 = bP0 + 65536;

  // stage addressing: thread covers dest rows {srow, srow+128}, 16B each
  int srow = tid >> 2;
  int seoff = (((tid & 3) ^ ((srow >> 1) & 3))) << 3;  // inverse-swizzled elem off
  const char* Ab = (const char*)A + ((size_t)(m0 + srow) * K + seoff) * 2;
  const char* Bb = (const char*)Bt + ((size_t)(n0 + srow) * K + seoff) * 2;
  size_t rstep = (size_t)K * 256;  // 128 rows

  auto stg = [&](int mat, int kh, int buf, int tile) {
    const char* gp = (mat ? Bb : Ab) + tile * 128 + kh * 64;
    unsigned short* lp = lds + buf * 32768 + mat * 16384 + kh * 8192 + w * 512;
    gload16((const unsigned short*)gp, lp);
    gload16((const unsigned short*)(gp + rstep), lp + 4096);
  };
  auto nop = [&] {};

  f32x4 acc[8][4] = {};
  s16x8 bk[4];
  int NT = K / 64;

  // prologue: t0 fully + t1 {Bk0, Ak0, Bk1}; force t0 complete
  stg(1, 0, 0, 0);
  stg(0, 0, 0, 0);
  stg(1, 1, 0, 0);
  stg(0, 1, 0, 0);
  stg(1, 0, 1, 1);
  stg(0, 0, 1, 1);
  stg(1, 1, 1, 1);
  asm volatile("s_waitcnt vmcnt(6)");
  __builtin_amdgcn_s_barrier();

  for (int t = 0; t + 3 < NT; t += 2) {
    gphase<0, 0, 0, -1>(aP0, aP1, bP0, bP1, bk, acc, [&] { stg(0, 1, 1, t + 1); });
    gphase<0, 1, 0, 10>(aP0, aP1, bP0, bP1, bk, acc, [&] { stg(1, 0, 0, t + 2); });
    gphase<0, 0, 1, -1>(aP0, aP1, bP0, bP1, bk, acc, [&] { stg(0, 0, 0, t + 2); });
    gphase<0, 1, 1, 10>(aP0, aP1, bP0, bP1, bk, acc, [&] { stg(1, 1, 0, t + 2); });
    gphase<1, 0, 0, -1>(aP0, aP1, bP0, bP1, bk, acc, [&] { stg(0, 1, 0, t + 2); });
    gphase<1, 1, 0, 10>(aP0, aP1, bP0, bP1, bk, acc, [&] { stg(1, 0, 1, t + 3); });
    gphase<1, 0, 1, -1>(aP0, aP1, bP0, bP1, bk, acc, [&] { stg(0, 0, 1, t + 3); });
    gphase<1, 1, 1, 10>(aP0, aP1, bP0, bP1, bk, acc, [&] { stg(1, 1, 1, t + 3); });
  }
  // epilogue iteration: compute {NT-2, NT-1}; outstanding after ph1 = 8 loads
  gphase<0, 0, 0, -1>(aP0, aP1, bP0, bP1, bk, acc, [&] { stg(0, 1, 1, NT - 1); });
  gphase<0, 1, 0, -1>(aP0, aP1, bP0, bP1, bk, acc, nop);
  gphase<0, 0, 1, -1>(aP0, aP1, bP0, bP1, bk, acc, nop);
  gphase<0, 1, 1, 4>(aP0, aP1, bP0, bP1, bk, acc, nop);
  gphase<1, 0, 0, -1>(aP0, aP1, bP0, bP1, bk, acc, nop);
  gphase<1, 1, 0, 0>(aP0, aP1, bP0, bP1, bk, acc, nop);
  gphase<1, 0, 1, -1>(aP0, aP1, bP0, bP1, bk, acc, nop);
  gphase<1, 1, 1, -1>(aP0, aP1, bP0, bP1, bk, acc, nop);

  // C write: row = m0 + wm*128 + am*16 + q*4 + rr, col = n0 + wn*64 + ni*16 + fr
#pragma unroll
  for (int am = 0; am < 8; ++am) {
#pragma unroll
    for (int ni = 0; ni < 4; ++ni) {
#pragma unroll
      for (int rr = 0; rr < 4; ++rr) {
        int row = m0 + wm * 128 + am * 16 + q * 4 + rr;
        int col = n0 + wn * 64 + ni * 16 + fr;
        size_t idx = (size_t)row * N + col;
        float v = acc[am][ni][rr];
        if (EPI == 0) {
          ((unsigned short*)outp)[idx] = f2bs(v);
        } else if (EPI == 2) {
          float t = v + bias[col];
          float arg = 1.5957691216f * t * (1.f + 0.044715f * t * t);
          float gl = t * __builtin_amdgcn_rcpf(1.f + __expf(-arg));
          ((unsigned short*)outp)[idx] = f2bs(gl);
        } else if (EPI == 3) {
          float t = v + bias[col] + ((const float*)resid)[idx];
          ((unsigned short*)outp)[idx] = f2bs(t);
        } else {
          float t = v + bias[col] + bs2f(((const unsigned short*)resid)[idx]);
          ((float*)outp)[idx] = t;
        }
      }
    }
  }
}

// distinct names for rocprof attribution
__global__ __launch_bounds__(512, 2) void gemm_qkv(const unsigned short* A,
                                                   const unsigned short* Bt, void* o,
                                                   const float* b, const void* r, int M,
                                                   int N, int K, int ntn) {
  gemm8_body<0>(A, Bt, o, b, r, M, N, K, ntn);
}
__global__ __launch_bounds__(512, 2) void gemm_proj(const unsigned short* A,
                                                    const unsigned short* Bt, void* o,
                                                    const float* b, const void* r, int M,
                                                    int N, int K, int ntn) {
  gemm8_body<3>(A, Bt, o, b, r, M, N, K, ntn);
}
__global__ __launch_bounds__(512, 2) void gemm_mlp1(const unsigned short* A,
                                                    const unsigned short* Bt, void* o,
                                                    const float* b, const void* r, int M,
                                                    int N, int K, int ntn) {
  gemm8_body<2>(A, Bt, o, b, r, M, N, K, ntn);
}
__global__ __launch_bounds__(512, 2) void gemm_mlp2(const unsigned short* A,
                                                    const unsigned short* Bt, void* o,
                                                    const float* b, const void* r, int M,
                                                    int N, int K, int ntn) {
  gemm8_body<4>(A, Bt, o, b, r, M, N, K, ntn);
}

// ---------------- MFMA attention: one wave per (batch, head) ----------------
__global__ __launch_bounds__(256) void attn_mfma_kernel(const unsigned short* __restrict__ qkv,
                                                        const float* __restrict__ scale,
                                                        unsigned short* __restrict__ ao) {
  __shared__ unsigned short Vt[4][64][40];  // 20480 B
  __shared__ unsigned short Pl[4][32][32];  // 8192 B
  int wid = threadIdx.x >> 6, lane = threadIdx.x & 63;
  int pair = blockIdx.x * 4 + wid;
  int b = pair / HEADS, h = pair % HEADS;
  const unsigned short* base = qkv + (size_t)b * NTOK * QKVN + h * DHEAD;
  const unsigned short* Qp = base;
  const unsigned short* Kp = base + 768;
  const unsigned short* Vp = base + 1536;

  int c = lane & 15, q = lane >> 4;
  int oct = q * 8;

  // ---- stage V transposed: lane owns V^T row d=lane ----
  unsigned short vcol[NTOK];
#pragma unroll
  for (int j = 0; j < NTOK; ++j) vcol[j] = Vp[(size_t)j * QKVN + lane];
#pragma unroll
  for (int j = 0; j < NTOK; ++j) Vt[wid][lane][j] = vcol[j];
  Vt[wid][lane][31] = 0;  // padded key column

  // ---- load Q,K fragments (rows >= 31 zeroed) ----
  s16x8 kf[2][2] = {{{0}}}, qf[2][2] = {{{0}}};
#pragma unroll
  for (int t = 0; t < 2; ++t) {
    int row = t * 16 + c;
    if (row < NTOK) {
#pragma unroll
      for (int s = 0; s < 2; ++s) {
        kf[t][s] = *(const s16x8*)(Kp + (size_t)row * QKVN + s * 32 + oct);
        qf[t][s] = *(const s16x8*)(Qp + (size_t)row * QKVN + s * 32 + oct);
      }
    }
  }

  // ---- S^T = K·Q^T ----
  f32x4 st[2][2] = {};
#pragma unroll
  for (int jt = 0; jt < 2; ++jt)
#pragma unroll
    for (int it = 0; it < 2; ++it)
#pragma unroll
      for (int s = 0; s < 2; ++s)
        st[jt][it] =
            __builtin_amdgcn_mfma_f32_16x16x32_bf16(kf[jt][s], qf[it][s], st[jt][it], 0, 0, 0);

  float scl = scale[h];
  // scale + diagonal/pad mask; value (jt,it,r): j=jt*16+4q+r, i=it*16+c
  float p[2][2][4];
#pragma unroll
  for (int it = 0; it < 2; ++it)
#pragma unroll
    for (int jt = 0; jt < 2; ++jt)
#pragma unroll
      for (int r = 0; r < 4; ++r) {
        int j = jt * 16 + 4 * q + r;
        int i = it * 16 + c;
        float v = st[jt][it][r] * scl;
        if (j == 31 || j == i) v = MASK_VAL;
        p[it][jt][r] = v;
      }
  // softmax per column i (4 lanes hold a column: xor16, xor32)
#pragma unroll
  for (int it = 0; it < 2; ++it) {
    float m = p[it][0][0];
#pragma unroll
    for (int jt = 0; jt < 2; ++jt)
#pragma unroll
      for (int r = 0; r < 4; ++r) m = fmaxf(m, p[it][jt][r]);
    m = fmaxf(m, __shfl_xor(m, 16));
    m = fmaxf(m, __shfl_xor(m, 32));
    float s = 0.f;
#pragma unroll
    for (int jt = 0; jt < 2; ++jt)
#pragma unroll
      for (int r = 0; r < 4; ++r) {
        float e = __expf(p[it][jt][r] - m);
        p[it][jt][r] = e;
        s += e;
      }
    s += __shfl_xor(s, 16);
    s += __shfl_xor(s, 32);
    float inv = __builtin_amdgcn_rcpf(s);
#pragma unroll
    for (int jt = 0; jt < 2; ++jt)
#pragma unroll
      for (int r = 0; r < 4; ++r) p[it][jt][r] *= inv;
  }
  // P -> LDS [i][j] (rows i, j-contiguous quads)
#pragma unroll
  for (int it = 0; it < 2; ++it)
#pragma unroll
    for (int jt = 0; jt < 2; ++jt) {
      unsigned int w0 =
          (unsigned int)f2bs(p[it][jt][0]) | ((unsigned int)f2bs(p[it][jt][1]) << 16);
      unsigned int w1 =
          (unsigned int)f2bs(p[it][jt][2]) | ((unsigned int)f2bs(p[it][jt][3]) << 16);
      uint2 pk = {w0, w1};
      *(uint2*)&Pl[wid][it * 16 + c][jt * 16 + 4 * q] = pk;
    }

  // ---- O = P·V ----
  s16x8 pa[2];
#pragma unroll
  for (int it = 0; it < 2; ++it) pa[it] = *(const s16x8*)&Pl[wid][it * 16 + c][oct];
  f32x4 o[2][4];
#pragma unroll
  for (int it = 0; it < 2; ++it)
#pragma unroll
    for (int dt = 0; dt < 4; ++dt) {
      s16x8 vb = *(const s16x8*)&Vt[wid][dt * 16 + c][oct];
      f32x4 z = {0.f, 0.f, 0.f, 0.f};
      o[it][dt] = __builtin_amdgcn_mfma_f32_16x16x32_bf16(pa[it], vb, z, 0, 0, 0);
    }
  // store: row i = it*16+4q+r (skip i==31), col d = dt*16+c
#pragma unroll
  for (int it = 0; it < 2; ++it)
#pragma unroll
    for (int r = 0; r < 4; ++r) {
      int i = it * 16 + 4 * q + r;
      if (i < NTOK) {
        size_t rowoff = ((size_t)b * NTOK + i) * DIM + h * DHEAD;
#pragma unroll
        for (int dt = 0; dt < 4; ++dt) ao[rowoff + dt * 16 + c] = f2bs(o[it][dt][r]);
      }
    }
}

// ---------------- launcher ----------------
// Workspace (peak 209,190,912 B < 256 MiB):
//   buf1 @ 0          (24,379,392): h -> ao -> h2
//   qkv/x2 @ 24,379,392 (73,138,176): qkv bf16, then x2 bf16 (qkv dead)
//   g    @ 97,517,568 (97,517,568): MLP hidden bf16
//   wT   @ 195,035,136 (14,155,776): pre-transposed bf16 weights
extern "C" void kernel_launch(void* const* d_in, const int* in_sizes, int n_in,
                              void* d_out, int out_size, void* d_ws, size_t ws_size,
                              hipStream_t stream) {
  (void)in_sizes; (void)n_in; (void)out_size; (void)ws_size;
  const float* x = (const float*)d_in[0];
  const float* ln1_g = (const float*)d_in[1];
  const float* ln1_b = (const float*)d_in[2];
  const float* w_qkv = (const float*)d_in[3];
  const float* scale = (const float*)d_in[4];
  const float* w_o = (const float*)d_in[5];
  const float* b_o = (const float*)d_in[6];
  const float* ln2_g = (const float*)d_in[7];
  const float* ln2_b = (const float*)d_in[8];
  const float* w1 = (const float*)d_in[9];
  const float* b1 = (const float*)d_in[10];
  const float* w2 = (const float*)d_in[11];
  const float* b2 = (const float*)d_in[12];

  char* ws = (char*)d_ws;
  unsigned short* buf1 = (unsigned short*)(ws + 0);
  unsigned short* qkv_bf = (unsigned short*)(ws + 24379392);
  unsigned short* x2 = (unsigned short*)(ws + 24379392);  // aliases qkv (qkv dead)
  unsigned short* g_bf = (unsigned short*)(ws + 97517568);
  unsigned short* wqkvT = (unsigned short*)(ws + 195035136);  // [2304][768]
  unsigned short* woT = (unsigned short*)(ws + 198574080);    // [768][768]
  unsigned short* w1T = (unsigned short*)(ws + 199753728);    // [3072][768]
  unsigned short* w2T = (unsigned short*)(ws + 204472320);    // [768][3072]

  transpose_kernel<<<dim3(QKVN / 64, DIM / 64), 256, 0, stream>>>(w_qkv, wqkvT, DIM, QKVN);
  transpose_kernel<<<dim3(DIM / 64, DIM / 64), 256, 0, stream>>>(w_o, woT, DIM, DIM);
  transpose_kernel<<<dim3(HIDDEN / 64, DIM / 64), 256, 0, stream>>>(w1, w1T, DIM, HIDDEN);
  transpose_kernel<<<dim3(DIM / 64, HIDDEN / 64), 256, 0, stream>>>(w2, w2T, HIDDEN, DIM);

  ln_kernel<<<MTOK / 4, 256, 0, stream>>>(x, ln1_g, ln1_b, buf1);
  gemm_qkv<<<(MTOK / 256) * (QKVN / 256), 512, 0, stream>>>(
      buf1, wqkvT, qkv_bf, nullptr, nullptr, MTOK, QKVN, DIM, QKVN / 256);
  attn_mfma_kernel<<<(BATCH * HEADS) / 4, 256, 0, stream>>>(qkv_bf, scale, buf1);
  // proj + residual(x, f32) -> x2 (bf16)
  gemm_proj<<<(MTOK / 256) * (DIM / 256), 512, 0, stream>>>(
      buf1, woT, x2, b_o, x, MTOK, DIM, DIM, DIM / 256);
  ln_bf16_kernel<<<MTOK / 4, 256, 0, stream>>>(x2, ln2_g, ln2_b, buf1);
  // mlp1 + tanh-GELU
  gemm_mlp1<<<(MTOK / 256) * (HIDDEN / 256), 512, 0, stream>>>(
      buf1, w1T, g_bf, b1, nullptr, MTOK, HIDDEN, DIM, HIDDEN / 256);
  // mlp2 + residual(x2, bf16) -> out (f32)
  gemm_mlp2<<<(MTOK / 256) * (DIM / 256), 512, 0, stream>>>(
      g_bf, w2T, (float*)d_out, b2, x2, MTOK, DIM, HIDDEN, DIM / 256);
}

// Round 9
// 330.267 us; speedup vs baseline: 1.0578x; 1.0363x over previous
//
#include <hip/hip_runtime.h>
#include <math.h>

#define DIM 768
#define HEADS 12
#define DHEAD 64
#define NTOK 31
#define BATCH 512
#define MTOK (BATCH * NTOK)   /* 15872 */
#define HIDDEN 3072
#define QKVN 2304
#define MASK_VAL -987654321.0f

typedef short s16x8 __attribute__((ext_vector_type(8)));
typedef float f32x4 __attribute__((ext_vector_type(4)));

static __device__ __forceinline__ float bs2f(unsigned short u) {
  unsigned int x = ((unsigned int)u) << 16;
  return __builtin_bit_cast(float, x);
}
static __device__ __forceinline__ unsigned short f2bs(float f) {
  unsigned int x = __builtin_bit_cast(unsigned int, f);
  x += 0x7fffu + ((x >> 16) & 1u);
  return (unsigned short)(x >> 16);
}

// async global->LDS, 16B per lane, wave-uniform LDS base + lane*16
static __device__ __forceinline__ void gload16(const unsigned short* g, unsigned short* l) {
  __builtin_amdgcn_global_load_lds(
      (const __attribute__((address_space(1))) unsigned int*)g,
      (__attribute__((address_space(3))) unsigned int*)l, 16, 0, 0);
}

static __device__ __forceinline__ float epi_apply(int EPI, float v, int col, size_t idx,
                                                  const float* bias, const void* resid) {
  if (EPI == 0) return v;
  if (EPI == 2) {
    float t = v + bias[col];
    float arg = 1.5957691216f * t * (1.f + 0.044715f * t * t);
    return t * __builtin_amdgcn_rcpf(1.f + __expf(-arg));
  }
  if (EPI == 3) return v + bias[col] + ((const float*)resid)[idx];
  return v + bias[col] + bs2f(((const unsigned short*)resid)[idx]);  // EPI==4
}

static __device__ __forceinline__ void epi_store(int EPI, void* outp, size_t idx, float t) {
  if (EPI == 4) ((float*)outp)[idx] = t;
  else ((unsigned short*)outp)[idx] = f2bs(t);
}

// ---------------- weight transpose: w[K][N] f32 -> wt[N][K] bf16 ----------------
__global__ __launch_bounds__(256) void transpose_kernel(const float* __restrict__ w,
                                                        unsigned short* __restrict__ wt,
                                                        int K, int N) {
  __shared__ float t[64][65];
  int k0 = blockIdx.y * 64, n0 = blockIdx.x * 64;
  int tid = threadIdx.x;
  int r = tid >> 4, c4 = (tid & 15) * 4;
#pragma unroll
  for (int i = 0; i < 4; ++i) {
    float4 v = *(const float4*)(w + (size_t)(k0 + r + i * 16) * N + n0 + c4);
    t[r + i * 16][c4] = v.x;
    t[r + i * 16][c4 + 1] = v.y;
    t[r + i * 16][c4 + 2] = v.z;
    t[r + i * 16][c4 + 3] = v.w;
  }
  __syncthreads();
#pragma unroll
  for (int i = 0; i < 4; ++i) {
    int n = r + i * 16;
    ushort4 o;
    o.x = f2bs(t[c4 + 0][n]);
    o.y = f2bs(t[c4 + 1][n]);
    o.z = f2bs(t[c4 + 2][n]);
    o.w = f2bs(t[c4 + 3][n]);
    *(ushort4*)(wt + (size_t)(n0 + n) * K + k0 + c4) = o;
  }
}

// ---------------- LayerNorm (f32 in) ----------------
__global__ __launch_bounds__(256) void ln_kernel(const float* __restrict__ x,
                                                 const float* __restrict__ g,
                                                 const float* __restrict__ bta,
                                                 unsigned short* __restrict__ out) {
  int wid = threadIdx.x >> 6, lane = threadIdx.x & 63;
  size_t row = (size_t)blockIdx.x * 4 + wid;
  const float4* xr = (const float4*)(x + row * DIM);
  float4 v[3];
  v[0] = xr[lane];
  v[1] = xr[lane + 64];
  v[2] = xr[lane + 128];
  float s = 0.f, sq = 0.f;
#pragma unroll
  for (int i = 0; i < 3; ++i) {
    s += v[i].x + v[i].y + v[i].z + v[i].w;
    sq += v[i].x * v[i].x + v[i].y * v[i].y + v[i].z * v[i].z + v[i].w * v[i].w;
  }
#pragma unroll
  for (int off = 32; off; off >>= 1) {
    s += __shfl_xor(s, off);
    sq += __shfl_xor(sq, off);
  }
  float mu = s * (1.f / DIM);
  float var = sq * (1.f / DIM) - mu * mu;
  float rs = rsqrtf(var + 1e-5f);
#pragma unroll
  for (int i = 0; i < 3; ++i) {
    int col = i * 256 + lane * 4;
    float4 gg = *(const float4*)(g + col);
    float4 bb = *(const float4*)(bta + col);
    ushort4 o;
    o.x = f2bs((v[i].x - mu) * rs * gg.x + bb.x);
    o.y = f2bs((v[i].y - mu) * rs * gg.y + bb.y);
    o.z = f2bs((v[i].z - mu) * rs * gg.z + bb.z);
    o.w = f2bs((v[i].w - mu) * rs * gg.w + bb.w);
    *(ushort4*)(out + row * DIM + col) = o;
  }
}

// ---------------- LayerNorm (bf16 in) ----------------
__global__ __launch_bounds__(256) void ln_bf16_kernel(const unsigned short* __restrict__ x,
                                                      const float* __restrict__ g,
                                                      const float* __restrict__ bta,
                                                      unsigned short* __restrict__ out) {
  int wid = threadIdx.x >> 6, lane = threadIdx.x & 63;
  size_t row = (size_t)blockIdx.x * 4 + wid;
  const unsigned short* xr = x + row * DIM;
  float v[12];
#pragma unroll
  for (int i = 0; i < 3; ++i) {
    ushort4 u = *(const ushort4*)(xr + i * 256 + lane * 4);
    v[i * 4 + 0] = bs2f(u.x);
    v[i * 4 + 1] = bs2f(u.y);
    v[i * 4 + 2] = bs2f(u.z);
    v[i * 4 + 3] = bs2f(u.w);
  }
  float s = 0.f, sq = 0.f;
#pragma unroll
  for (int i = 0; i < 12; ++i) {
    s += v[i];
    sq += v[i] * v[i];
  }
#pragma unroll
  for (int off = 32; off; off >>= 1) {
    s += __shfl_xor(s, off);
    sq += __shfl_xor(sq, off);
  }
  float mu = s * (1.f / DIM);
  float var = sq * (1.f / DIM) - mu * mu;
  float rs = rsqrtf(var + 1e-5f);
#pragma unroll
  for (int i = 0; i < 3; ++i) {
    int col = i * 256 + lane * 4;
    float4 gg = *(const float4*)(g + col);
    float4 bb = *(const float4*)(bta + col);
    ushort4 o;
    o.x = f2bs((v[i * 4 + 0] - mu) * rs * gg.x + bb.x);
    o.y = f2bs((v[i * 4 + 1] - mu) * rs * gg.y + bb.y);
    o.z = f2bs((v[i * 4 + 2] - mu) * rs * gg.z + bb.z);
    o.w = f2bs((v[i * 4 + 3] - mu) * rs * gg.w + bb.w);
    *(ushort4*)(out + row * DIM + col) = o;
  }
}

// ================= 8-phase 256x256 GEMM (proven path: qkv, mlp1) =================
template <int BUF, int MH, int KH, int VM, typename STF>
__device__ __forceinline__ void gphase(const char* aP0, const char* aP1,
                                       const char* bP0, const char* bP1,
                                       s16x8* bk, f32x4 (&acc)[8][4], STF&& stage) {
  const char* aP = BUF ? aP1 : aP0;
  const char* bP = BUF ? bP1 : bP0;
  s16x8 af[4];
  if (MH == 0) {
#pragma unroll
    for (int ni = 0; ni < 4; ++ni)
      bk[ni] = *(const s16x8*)(bP + KH * 16384 + ni * 1024);
  }
#pragma unroll
  for (int mi = 0; mi < 4; ++mi)
    af[mi] = *(const s16x8*)(aP + KH * 16384 + MH * 4096 + mi * 1024);
  stage();
  if (VM == 10) asm volatile("s_waitcnt vmcnt(10)");
  if (VM == 4) asm volatile("s_waitcnt vmcnt(4)");
  if (VM == 0) asm volatile("s_waitcnt vmcnt(0)");
  __builtin_amdgcn_s_barrier();
  asm volatile("s_waitcnt lgkmcnt(0)");
  __builtin_amdgcn_s_setprio(1);
#pragma unroll
  for (int mi = 0; mi < 4; ++mi)
#pragma unroll
    for (int ni = 0; ni < 4; ++ni)
      acc[MH * 4 + mi][ni] =
          __builtin_amdgcn_mfma_f32_16x16x32_bf16(af[mi], bk[ni], acc[MH * 4 + mi][ni], 0, 0, 0);
  __builtin_amdgcn_s_setprio(0);
  __builtin_amdgcn_s_barrier();
}

template <int EPI>
__device__ __forceinline__ void gemm8_body(
    const unsigned short* __restrict__ A, const unsigned short* __restrict__ Bt,
    void* __restrict__ outp, const float* __restrict__ bias,
    const void* __restrict__ resid, int M, int N, int K, int ntn) {
  __shared__ unsigned short lds[65536];  // 128 KiB
  const char* ldsb = (const char*)lds;
  int tid = threadIdx.x;
  int lane = tid & 63, w = tid >> 6;
  int wm = w >> 2, wn = w & 3;
  int fr = lane & 15, q = lane >> 4;

  int nwg = gridDim.x, orig = blockIdx.x;
  int qd = nwg >> 3, r8 = nwg & 7, xcd = orig & 7, loc = orig >> 3;
  int bid = (xcd < r8 ? xcd * (qd + 1) : r8 * (qd + 1) + (xcd - r8) * qd) + loc;
  int m0 = (bid / ntn) * 256, n0 = (bid % ntn) * 256;

  int rdoff = (q * 16) ^ (((fr >> 1) & 3) << 4);
  const char* aP0 = ldsb + (wm * 128 + fr) * 64 + rdoff;
  const char* aP1 = aP0 + 65536;
  const char* bP0 = ldsb + 32768 + (wn * 64 + fr) * 64 + rdoff;
  const char* bP1 = bP0 + 65536;

  int srow = tid >> 2;
  int seoff = (((tid & 3) ^ ((srow >> 1) & 3))) << 3;
  const char* Ab = (const char*)A + ((size_t)(m0 + srow) * K + seoff) * 2;
  const char* Bb = (const char*)Bt + ((size_t)(n0 + srow) * K + seoff) * 2;
  size_t rstep = (size_t)K * 256;

  auto stg = [&](int mat, int kh, int buf, int tile) {
    const char* gp = (mat ? Bb : Ab) + tile * 128 + kh * 64;
    unsigned short* lp = lds + buf * 32768 + mat * 16384 + kh * 8192 + w * 512;
    gload16((const unsigned short*)gp, lp);
    gload16((const unsigned short*)(gp + rstep), lp + 4096);
  };
  auto nop = [&] {};

  f32x4 acc[8][4] = {};
  s16x8 bk[4];
  int NT = K / 64;

  stg(1, 0, 0, 0);
  stg(0, 0, 0, 0);
  stg(1, 1, 0, 0);
  stg(0, 1, 0, 0);
  stg(1, 0, 1, 1);
  stg(0, 0, 1, 1);
  stg(1, 1, 1, 1);
  asm volatile("s_waitcnt vmcnt(6)");
  __builtin_amdgcn_s_barrier();

  for (int t = 0; t + 3 < NT; t += 2) {
    gphase<0, 0, 0, -1>(aP0, aP1, bP0, bP1, bk, acc, [&] { stg(0, 1, 1, t + 1); });
    gphase<0, 1, 0, 10>(aP0, aP1, bP0, bP1, bk, acc, [&] { stg(1, 0, 0, t + 2); });
    gphase<0, 0, 1, -1>(aP0, aP1, bP0, bP1, bk, acc, [&] { stg(0, 0, 0, t + 2); });
    gphase<0, 1, 1, 10>(aP0, aP1, bP0, bP1, bk, acc, [&] { stg(1, 1, 0, t + 2); });
    gphase<1, 0, 0, -1>(aP0, aP1, bP0, bP1, bk, acc, [&] { stg(0, 1, 0, t + 2); });
    gphase<1, 1, 0, 10>(aP0, aP1, bP0, bP1, bk, acc, [&] { stg(1, 0, 1, t + 3); });
    gphase<1, 0, 1, -1>(aP0, aP1, bP0, bP1, bk, acc, [&] { stg(0, 0, 1, t + 3); });
    gphase<1, 1, 1, 10>(aP0, aP1, bP0, bP1, bk, acc, [&] { stg(1, 1, 1, t + 3); });
  }
  gphase<0, 0, 0, -1>(aP0, aP1, bP0, bP1, bk, acc, [&] { stg(0, 1, 1, NT - 1); });
  gphase<0, 1, 0, -1>(aP0, aP1, bP0, bP1, bk, acc, nop);
  gphase<0, 0, 1, -1>(aP0, aP1, bP0, bP1, bk, acc, nop);
  gphase<0, 1, 1, 4>(aP0, aP1, bP0, bP1, bk, acc, nop);
  gphase<1, 0, 0, -1>(aP0, aP1, bP0, bP1, bk, acc, nop);
  gphase<1, 1, 0, 0>(aP0, aP1, bP0, bP1, bk, acc, nop);
  gphase<1, 0, 1, -1>(aP0, aP1, bP0, bP1, bk, acc, nop);
  gphase<1, 1, 1, -1>(aP0, aP1, bP0, bP1, bk, acc, nop);

#pragma unroll
  for (int am = 0; am < 8; ++am)
#pragma unroll
    for (int ni = 0; ni < 4; ++ni)
#pragma unroll
      for (int rr = 0; rr < 4; ++rr) {
        int row = m0 + wm * 128 + am * 16 + (lane >> 4) * 4 + rr;
        int col = n0 + wn * 64 + ni * 16 + fr;
        size_t idx = (size_t)row * N + col;
        epi_store(EPI, outp, idx, epi_apply(EPI, acc[am][ni][rr], col, idx, bias, resid));
      }
}

// ================= 8-phase 256x192 GEMM (fill path: proj, mlp2) =================
// LDS 112 KiB: A [buf][kh][256][32] @0 (32KB/buf); B [buf][192][64] @65536 (24KB/buf).
// B rows 128 B, swizzle slot ^= (row&7); inverse-swizzled global source (3 uniform
// wave-issues per B tile). Waits: vmcnt(2)@ph4/ph8 steady; epilogue vmcnt(0)@ph4.
template <int BUF, int MH, int KH, int VM, typename STF>
__device__ __forceinline__ void gph192(const char* aB0, const char* bKH0, const char* bKH1,
                                       s16x8 (&bk)[3], f32x4 (&acc)[8][3], STF&& stage) {
  const char* aP = aB0 + BUF * 32768 + KH * 16384 + MH * 4096;
  s16x8 af[4];
  if (MH == 0) {
    const char* bp = (KH ? bKH1 : bKH0) + BUF * 24576;
#pragma unroll
    for (int ni = 0; ni < 3; ++ni) bk[ni] = *(const s16x8*)(bp + ni * 2048);
  }
#pragma unroll
  for (int mi = 0; mi < 4; ++mi) af[mi] = *(const s16x8*)(aP + mi * 1024);
  stage();
  if (VM == 2) asm volatile("s_waitcnt vmcnt(2)");
  if (VM == 0) asm volatile("s_waitcnt vmcnt(0)");
  __builtin_amdgcn_s_barrier();
  asm volatile("s_waitcnt lgkmcnt(0)");
  __builtin_amdgcn_s_setprio(1);
#pragma unroll
  for (int mi = 0; mi < 4; ++mi)
#pragma unroll
    for (int ni = 0; ni < 3; ++ni)
      acc[MH * 4 + mi][ni] =
          __builtin_amdgcn_mfma_f32_16x16x32_bf16(af[mi], bk[ni], acc[MH * 4 + mi][ni], 0, 0, 0);
  __builtin_amdgcn_s_setprio(0);
  __builtin_amdgcn_s_barrier();
}

template <int EPI>
__device__ __forceinline__ void gemm192_body(
    const unsigned short* __restrict__ A, const unsigned short* __restrict__ Bt,
    void* __restrict__ outp, const float* __restrict__ bias,
    const void* __restrict__ resid, int M, int N, int K, int ntn) {
  __shared__ char ldsc[114688];  // 112 KiB
  int tid = threadIdx.x;
  int lane = tid & 63, w = tid >> 6;
  int wm = w >> 2, wn = w & 3;
  int fr = lane & 15, q = lane >> 4;

  int nwg = gridDim.x, orig = blockIdx.x;
  int qd = nwg >> 3, r8 = nwg & 7, xcd = orig & 7, loc = orig >> 3;
  int bid = (xcd < r8 ? xcd * (qd + 1) : r8 * (qd + 1) + (xcd - r8) * qd) + loc;
  int m0 = (bid / ntn) * 256, n0 = (bid % ntn) * 192;

  // A frag base (proven swizzle, rows 64 B)
  int rdoffA = (q * 16) ^ (((fr >> 1) & 3) << 4);
  const char* aB0 = ldsc + (wm * 128 + fr) * 64 + rdoffA;
  // B frag bases (rows 128 B, slot = kh*4+q, swizzle slot^=(row&7))
  int brow0 = wn * 48 + fr;
  int bsw = brow0 & 7;
  const char* bBase = ldsc + 65536 + brow0 * 128 + (q ^ (bsw & 3)) * 16;
  const char* bKH0 = bBase + ((0 ^ (bsw >> 2)) * 64);
  const char* bKH1 = bBase + ((1 ^ (bsw >> 2)) * 64);

  // A stage (identical to proven path)
  int srow = tid >> 2;
  int seoffA = (((tid & 3) ^ ((srow >> 1) & 3))) << 3;
  const char* Ab = (const char*)A + ((size_t)(m0 + srow) * K + seoffA) * 2;
  size_t rstep = (size_t)K * 256;
  auto stgA = [&](int kh, int buf, int tile) {
    const char* gp = Ab + tile * 128 + kh * 64;
    unsigned short* lp = (unsigned short*)(ldsc + buf * 32768 + kh * 16384 + w * 1024);
    gload16((const unsigned short*)gp, lp);
    gload16((const unsigned short*)(gp + rstep), (unsigned short*)((char*)lp + 8192));
  };
  // B stage: issue j covers rows j*64+(tid>>3), slot tid&7; src octet = slot^(row&7)
  const char* Bb2 = (const char*)Bt +
                    ((size_t)(n0 + (tid >> 3)) * K + (((tid & 7) ^ ((tid >> 3) & 7)) * 8)) * 2;
  auto stgB = [&](int j, int buf, int tile) {
    gload16((const unsigned short*)(Bb2 + (size_t)j * 128 * K + tile * 128),
            (unsigned short*)(ldsc + 65536 + buf * 24576 + j * 8192 + w * 1024));
  };
  auto nop = [&] {};

  f32x4 acc[8][3] = {};
  s16x8 bk[3];
  int NT = K / 64;

  // prologue: t0 full (7) + t1 A-kh0 (2); wait t0 done
  stgA(0, 0, 0);
  stgA(1, 0, 0);
  stgB(0, 0, 0);
  stgB(1, 0, 0);
  stgB(2, 0, 0);
  stgA(0, 1, 1);
  asm volatile("s_waitcnt vmcnt(2)");
  __builtin_amdgcn_s_barrier();

  for (int t = 0; t + 3 < NT; t += 2) {
    gph192<0, 0, 0, -1>(aB0, bKH0, bKH1, bk, acc,
                        [&] { stgA(1, 1, t + 1); stgB(0, 1, t + 1); stgB(1, 1, t + 1); });
    gph192<0, 1, 0, -1>(aB0, bKH0, bKH1, bk, acc, [&] { stgB(2, 1, t + 1); });
    gph192<0, 0, 1, -1>(aB0, bKH0, bKH1, bk, acc, [&] { stgA(0, 0, t + 2); });
    gph192<0, 1, 1, 2>(aB0, bKH0, bKH1, bk, acc, nop);
    gph192<1, 0, 0, -1>(aB0, bKH0, bKH1, bk, acc,
                        [&] { stgA(1, 0, t + 2); stgB(0, 0, t + 2); stgB(1, 0, t + 2); });
    gph192<1, 1, 0, -1>(aB0, bKH0, bKH1, bk, acc, [&] { stgB(2, 0, t + 2); });
    gph192<1, 0, 1, -1>(aB0, bKH0, bKH1, bk, acc, [&] { stgA(0, 1, t + 3); });
    gph192<1, 1, 1, 2>(aB0, bKH0, bKH1, bk, acc, nop);
  }
  // epilogue: computes {NT-2, NT-1}; finish staging NT-1, drain at ph4
  gph192<0, 0, 0, -1>(aB0, bKH0, bKH1, bk, acc,
                      [&] { stgA(1, 1, NT - 1); stgB(0, 1, NT - 1); stgB(1, 1, NT - 1); });
  gph192<0, 1, 0, -1>(aB0, bKH0, bKH1, bk, acc, [&] { stgB(2, 1, NT - 1); });
  gph192<0, 0, 1, -1>(aB0, bKH0, bKH1, bk, acc, nop);
  gph192<0, 1, 1, 0>(aB0, bKH0, bKH1, bk, acc, nop);
  gph192<1, 0, 0, -1>(aB0, bKH0, bKH1, bk, acc, nop);
  gph192<1, 1, 0, -1>(aB0, bKH0, bKH1, bk, acc, nop);
  gph192<1, 0, 1, -1>(aB0, bKH0, bKH1, bk, acc, nop);
  gph192<1, 1, 1, -1>(aB0, bKH0, bKH1, bk, acc, nop);

#pragma unroll
  for (int am = 0; am < 8; ++am)
#pragma unroll
    for (int ni = 0; ni < 3; ++ni)
#pragma unroll
      for (int rr = 0; rr < 4; ++rr) {
        int row = m0 + wm * 128 + am * 16 + q * 4 + rr;
        int col = n0 + wn * 48 + ni * 16 + fr;
        size_t idx = (size_t)row * N + col;
        epi_store(EPI, outp, idx, epi_apply(EPI, acc[am][ni][rr], col, idx, bias, resid));
      }
}

// named wrappers for rocprof attribution
__global__ __launch_bounds__(512, 2) void gemm_qkv(const unsigned short* A,
                                                   const unsigned short* Bt, void* o,
                                                   const float* b, const void* r, int M,
                                                   int N, int K, int ntn) {
  gemm8_body<0>(A, Bt, o, b, r, M, N, K, ntn);
}
__global__ __launch_bounds__(512, 2) void gemm_mlp1(const unsigned short* A,
                                                    const unsigned short* Bt, void* o,
                                                    const float* b, const void* r, int M,
                                                    int N, int K, int ntn) {
  gemm8_body<2>(A, Bt, o, b, r, M, N, K, ntn);
}
__global__ __launch_bounds__(512, 2) void gemm_proj(const unsigned short* A,
                                                    const unsigned short* Bt, void* o,
                                                    const float* b, const void* r, int M,
                                                    int N, int K, int ntn) {
  gemm192_body<3>(A, Bt, o, b, r, M, N, K, ntn);
}
__global__ __launch_bounds__(512, 2) void gemm_mlp2(const unsigned short* A,
                                                    const unsigned short* Bt, void* o,
                                                    const float* b, const void* r, int M,
                                                    int N, int K, int ntn) {
  gemm192_body<4>(A, Bt, o, b, r, M, N, K, ntn);
}

// ---------------- MFMA attention: one wave per (batch, head) ----------------
__global__ __launch_bounds__(256) void attn_mfma_kernel(const unsigned short* __restrict__ qkv,
                                                        const float* __restrict__ scale,
                                                        unsigned short* __restrict__ ao) {
  __shared__ unsigned short Vt[4][64][40];
  __shared__ unsigned short Pl[4][32][32];
  int wid = threadIdx.x >> 6, lane = threadIdx.x & 63;
  int pair = blockIdx.x * 4 + wid;
  int b = pair / HEADS, h = pair % HEADS;
  const unsigned short* base = qkv + (size_t)b * NTOK * QKVN + h * DHEAD;
  const unsigned short* Qp = base;
  const unsigned short* Kp = base + 768;
  const unsigned short* Vp = base + 1536;

  int c = lane & 15, q = lane >> 4;
  int oct = q * 8;

  unsigned short vcol[NTOK];
#pragma unroll
  for (int j = 0; j < NTOK; ++j) vcol[j] = Vp[(size_t)j * QKVN + lane];
#pragma unroll
  for (int j = 0; j < NTOK; ++j) Vt[wid][lane][j] = vcol[j];
  Vt[wid][lane][31] = 0;

  s16x8 kf[2][2] = {{{0}}}, qf[2][2] = {{{0}}};
#pragma unroll
  for (int t = 0; t < 2; ++t) {
    int row = t * 16 + c;
    if (row < NTOK) {
#pragma unroll
      for (int s = 0; s < 2; ++s) {
        kf[t][s] = *(const s16x8*)(Kp + (size_t)row * QKVN + s * 32 + oct);
        qf[t][s] = *(const s16x8*)(Qp + (size_t)row * QKVN + s * 32 + oct);
      }
    }
  }

  f32x4 st[2][2] = {};
#pragma unroll
  for (int jt = 0; jt < 2; ++jt)
#pragma unroll
    for (int it = 0; it < 2; ++it)
#pragma unroll
      for (int s = 0; s < 2; ++s)
        st[jt][it] =
            __builtin_amdgcn_mfma_f32_16x16x32_bf16(kf[jt][s], qf[it][s], st[jt][it], 0, 0, 0);

  float scl = scale[h];
  float p[2][2][4];
#pragma unroll
  for (int it = 0; it < 2; ++it)
#pragma unroll
    for (int jt = 0; jt < 2; ++jt)
#pragma unroll
      for (int r = 0; r < 4; ++r) {
        int j = jt * 16 + 4 * q + r;
        int i = it * 16 + c;
        float v = st[jt][it][r] * scl;
        if (j == 31 || j == i) v = MASK_VAL;
        p[it][jt][r] = v;
      }
#pragma unroll
  for (int it = 0; it < 2; ++it) {
    float m = p[it][0][0];
#pragma unroll
    for (int jt = 0; jt < 2; ++jt)
#pragma unroll
      for (int r = 0; r < 4; ++r) m = fmaxf(m, p[it][jt][r]);
    m = fmaxf(m, __shfl_xor(m, 16));
    m = fmaxf(m, __shfl_xor(m, 32));
    float s = 0.f;
#pragma unroll
    for (int jt = 0; jt < 2; ++jt)
#pragma unroll
      for (int r = 0; r < 4; ++r) {
        float e = __expf(p[it][jt][r] - m);
        p[it][jt][r] = e;
        s += e;
      }
    s += __shfl_xor(s, 16);
    s += __shfl_xor(s, 32);
    float inv = __builtin_amdgcn_rcpf(s);
#pragma unroll
    for (int jt = 0; jt < 2; ++jt)
#pragma unroll
      for (int r = 0; r < 4; ++r) p[it][jt][r] *= inv;
  }
#pragma unroll
  for (int it = 0; it < 2; ++it)
#pragma unroll
    for (int jt = 0; jt < 2; ++jt) {
      unsigned int w0 =
          (unsigned int)f2bs(p[it][jt][0]) | ((unsigned int)f2bs(p[it][jt][1]) << 16);
      unsigned int w1 =
          (unsigned int)f2bs(p[it][jt][2]) | ((unsigned int)f2bs(p[it][jt][3]) << 16);
      uint2 pk = {w0, w1};
      *(uint2*)&Pl[wid][it * 16 + c][jt * 16 + 4 * q] = pk;
    }

  s16x8 pa[2];
#pragma unroll
  for (int it = 0; it < 2; ++it) pa[it] = *(const s16x8*)&Pl[wid][it * 16 + c][oct];
  f32x4 o[2][4];
#pragma unroll
  for (int it = 0; it < 2; ++it)
#pragma unroll
    for (int dt = 0; dt < 4; ++dt) {
      s16x8 vb = *(const s16x8*)&Vt[wid][dt * 16 + c][oct];
      f32x4 z = {0.f, 0.f, 0.f, 0.f};
      o[it][dt] = __builtin_amdgcn_mfma_f32_16x16x32_bf16(pa[it], vb, z, 0, 0, 0);
    }
#pragma unroll
  for (int it = 0; it < 2; ++it)
#pragma unroll
    for (int r = 0; r < 4; ++r) {
      int i = it * 16 + 4 * q + r;
      if (i < NTOK) {
        size_t rowoff = ((size_t)b * NTOK + i) * DIM + h * DHEAD;
#pragma unroll
        for (int dt = 0; dt < 4; ++dt) ao[rowoff + dt * 16 + c] = f2bs(o[it][dt][r]);
      }
    }
}

// ---------------- launcher ----------------
extern "C" void kernel_launch(void* const* d_in, const int* in_sizes, int n_in,
                              void* d_out, int out_size, void* d_ws, size_t ws_size,
                              hipStream_t stream) {
  (void)in_sizes; (void)n_in; (void)out_size; (void)ws_size;
  const float* x = (const float*)d_in[0];
  const float* ln1_g = (const float*)d_in[1];
  const float* ln1_b = (const float*)d_in[2];
  const float* w_qkv = (const float*)d_in[3];
  const float* scale = (const float*)d_in[4];
  const float* w_o = (const float*)d_in[5];
  const float* b_o = (const float*)d_in[6];
  const float* ln2_g = (const float*)d_in[7];
  const float* ln2_b = (const float*)d_in[8];
  const float* w1 = (const float*)d_in[9];
  const float* b1 = (const float*)d_in[10];
  const float* w2 = (const float*)d_in[11];
  const float* b2 = (const float*)d_in[12];

  char* ws = (char*)d_ws;
  unsigned short* buf1 = (unsigned short*)(ws + 0);
  unsigned short* qkv_bf = (unsigned short*)(ws + 24379392);
  unsigned short* x2 = (unsigned short*)(ws + 24379392);  // aliases qkv (qkv dead)
  unsigned short* g_bf = (unsigned short*)(ws + 97517568);
  unsigned short* wqkvT = (unsigned short*)(ws + 195035136);  // [2304][768]
  unsigned short* woT = (unsigned short*)(ws + 198574080);    // [768][768]
  unsigned short* w1T = (unsigned short*)(ws + 199753728);    // [3072][768]
  unsigned short* w2T = (unsigned short*)(ws + 204472320);    // [768][3072]

  transpose_kernel<<<dim3(QKVN / 64, DIM / 64), 256, 0, stream>>>(w_qkv, wqkvT, DIM, QKVN);
  transpose_kernel<<<dim3(DIM / 64, DIM / 64), 256, 0, stream>>>(w_o, woT, DIM, DIM);
  transpose_kernel<<<dim3(HIDDEN / 64, DIM / 64), 256, 0, stream>>>(w1, w1T, DIM, HIDDEN);
  transpose_kernel<<<dim3(DIM / 64, HIDDEN / 64), 256, 0, stream>>>(w2, w2T, HIDDEN, DIM);

  ln_kernel<<<MTOK / 4, 256, 0, stream>>>(x, ln1_g, ln1_b, buf1);
  gemm_qkv<<<(MTOK / 256) * (QKVN / 256), 512, 0, stream>>>(
      buf1, wqkvT, qkv_bf, nullptr, nullptr, MTOK, QKVN, DIM, QKVN / 256);
  attn_mfma_kernel<<<(BATCH * HEADS) / 4, 256, 0, stream>>>(qkv_bf, scale, buf1);
  // proj + residual(x, f32) -> x2 (bf16)   [256x192 tiles, grid 248]
  gemm_proj<<<(MTOK / 256) * (DIM / 192), 512, 0, stream>>>(
      buf1, woT, x2, b_o, x, MTOK, DIM, DIM, DIM / 192);
  ln_bf16_kernel<<<MTOK / 4, 256, 0, stream>>>(x2, ln2_g, ln2_b, buf1);
  // mlp1 + tanh-GELU   [256x256 tiles, grid 744]
  gemm_mlp1<<<(MTOK / 256) * (HIDDEN / 256), 512, 0, stream>>>(
      buf1, w1T, g_bf, b1, nullptr, MTOK, HIDDEN, DIM, HIDDEN / 256);
  // mlp2 + residual(x2, bf16) -> out (f32)   [256x192 tiles, grid 248]
  gemm_mlp2<<<(MTOK / 256) * (DIM / 192), 512, 0, stream>>>(
      g_bf, w2T, (float*)d_out, b2, x2, MTOK, DIM, HIDDEN, DIM / 192);
}

// Round 10
// 320.257 us; speedup vs baseline: 1.0908x; 1.0313x over previous
//
#include <hip/hip_runtime.h>
#include <math.h>

#define DIM 768
#define HEADS 12
#define DHEAD 64
#define NTOK 31
#define BATCH 512
#define MTOK (BATCH * NTOK)   /* 15872 */
#define HIDDEN 3072
#define QKVN 2304
#define MASK_VAL -987654321.0f

typedef short s16x8 __attribute__((ext_vector_type(8)));
typedef float f32x4 __attribute__((ext_vector_type(4)));

static __device__ __forceinline__ float bs2f(unsigned short u) {
  unsigned int x = ((unsigned int)u) << 16;
  return __builtin_bit_cast(float, x);
}
static __device__ __forceinline__ unsigned short f2bs(float f) {
  unsigned int x = __builtin_bit_cast(unsigned int, f);
  x += 0x7fffu + ((x >> 16) & 1u);
  return (unsigned short)(x >> 16);
}

// async global->LDS, 16B per lane, wave-uniform LDS base + lane*16
static __device__ __forceinline__ void gload16(const unsigned short* g, unsigned short* l) {
  __builtin_amdgcn_global_load_lds(
      (const __attribute__((address_space(1))) unsigned int*)g,
      (__attribute__((address_space(3))) unsigned int*)l, 16, 0, 0);
}

static __device__ __forceinline__ float epi_apply(int EPI, float v, int col, size_t idx,
                                                  const float* bias, const void* resid) {
  if (EPI == 0) return v;
  if (EPI == 2) {
    float t = v + bias[col];
    float arg = 1.5957691216f * t * (1.f + 0.044715f * t * t);
    return t * __builtin_amdgcn_rcpf(1.f + __expf(-arg));
  }
  if (EPI == 3) return v + bias[col] + ((const float*)resid)[idx];
  return v + bias[col] + bs2f(((const unsigned short*)resid)[idx]);  // EPI==4
}

static __device__ __forceinline__ void epi_store(int EPI, void* outp, size_t idx, float t) {
  if (EPI == 4) ((float*)outp)[idx] = t;
  else ((unsigned short*)outp)[idx] = f2bs(t);
}

// ---------------- weight transpose: w[K][N] f32 -> wt[N][K] bf16 ----------------
__global__ __launch_bounds__(256) void transpose_kernel(const float* __restrict__ w,
                                                        unsigned short* __restrict__ wt,
                                                        int K, int N) {
  __shared__ float t[64][65];
  int k0 = blockIdx.y * 64, n0 = blockIdx.x * 64;
  int tid = threadIdx.x;
  int r = tid >> 4, c4 = (tid & 15) * 4;
#pragma unroll
  for (int i = 0; i < 4; ++i) {
    float4 v = *(const float4*)(w + (size_t)(k0 + r + i * 16) * N + n0 + c4);
    t[r + i * 16][c4] = v.x;
    t[r + i * 16][c4 + 1] = v.y;
    t[r + i * 16][c4 + 2] = v.z;
    t[r + i * 16][c4 + 3] = v.w;
  }
  __syncthreads();
#pragma unroll
  for (int i = 0; i < 4; ++i) {
    int n = r + i * 16;
    ushort4 o;
    o.x = f2bs(t[c4 + 0][n]);
    o.y = f2bs(t[c4 + 1][n]);
    o.z = f2bs(t[c4 + 2][n]);
    o.w = f2bs(t[c4 + 3][n]);
    *(ushort4*)(wt + (size_t)(n0 + n) * K + k0 + c4) = o;
  }
}

// ---------------- LayerNorm (f32 in) ----------------
__global__ __launch_bounds__(256) void ln_kernel(const float* __restrict__ x,
                                                 const float* __restrict__ g,
                                                 const float* __restrict__ bta,
                                                 unsigned short* __restrict__ out) {
  int wid = threadIdx.x >> 6, lane = threadIdx.x & 63;
  size_t row = (size_t)blockIdx.x * 4 + wid;
  const float4* xr = (const float4*)(x + row * DIM);
  float4 v[3];
  v[0] = xr[lane];
  v[1] = xr[lane + 64];
  v[2] = xr[lane + 128];
  float s = 0.f, sq = 0.f;
#pragma unroll
  for (int i = 0; i < 3; ++i) {
    s += v[i].x + v[i].y + v[i].z + v[i].w;
    sq += v[i].x * v[i].x + v[i].y * v[i].y + v[i].z * v[i].z + v[i].w * v[i].w;
  }
#pragma unroll
  for (int off = 32; off; off >>= 1) {
    s += __shfl_xor(s, off);
    sq += __shfl_xor(sq, off);
  }
  float mu = s * (1.f / DIM);
  float var = sq * (1.f / DIM) - mu * mu;
  float rs = rsqrtf(var + 1e-5f);
#pragma unroll
  for (int i = 0; i < 3; ++i) {
    int col = i * 256 + lane * 4;
    float4 gg = *(const float4*)(g + col);
    float4 bb = *(const float4*)(bta + col);
    ushort4 o;
    o.x = f2bs((v[i].x - mu) * rs * gg.x + bb.x);
    o.y = f2bs((v[i].y - mu) * rs * gg.y + bb.y);
    o.z = f2bs((v[i].z - mu) * rs * gg.z + bb.z);
    o.w = f2bs((v[i].w - mu) * rs * gg.w + bb.w);
    *(ushort4*)(out + row * DIM + col) = o;
  }
}

// ---------------- LayerNorm (bf16 in) ----------------
__global__ __launch_bounds__(256) void ln_bf16_kernel(const unsigned short* __restrict__ x,
                                                      const float* __restrict__ g,
                                                      const float* __restrict__ bta,
                                                      unsigned short* __restrict__ out) {
  int wid = threadIdx.x >> 6, lane = threadIdx.x & 63;
  size_t row = (size_t)blockIdx.x * 4 + wid;
  const unsigned short* xr = x + row * DIM;
  float v[12];
#pragma unroll
  for (int i = 0; i < 3; ++i) {
    ushort4 u = *(const ushort4*)(xr + i * 256 + lane * 4);
    v[i * 4 + 0] = bs2f(u.x);
    v[i * 4 + 1] = bs2f(u.y);
    v[i * 4 + 2] = bs2f(u.z);
    v[i * 4 + 3] = bs2f(u.w);
  }
  float s = 0.f, sq = 0.f;
#pragma unroll
  for (int i = 0; i < 12; ++i) {
    s += v[i];
    sq += v[i] * v[i];
  }
#pragma unroll
  for (int off = 32; off; off >>= 1) {
    s += __shfl_xor(s, off);
    sq += __shfl_xor(sq, off);
  }
  float mu = s * (1.f / DIM);
  float var = sq * (1.f / DIM) - mu * mu;
  float rs = rsqrtf(var + 1e-5f);
#pragma unroll
  for (int i = 0; i < 3; ++i) {
    int col = i * 256 + lane * 4;
    float4 gg = *(const float4*)(g + col);
    float4 bb = *(const float4*)(bta + col);
    ushort4 o;
    o.x = f2bs((v[i * 4 + 0] - mu) * rs * gg.x + bb.x);
    o.y = f2bs((v[i * 4 + 1] - mu) * rs * gg.y + bb.y);
    o.z = f2bs((v[i * 4 + 2] - mu) * rs * gg.z + bb.z);
    o.w = f2bs((v[i * 4 + 3] - mu) * rs * gg.w + bb.w);
    *(ushort4*)(out + row * DIM + col) = o;
  }
}

// ================= 8-phase 256x256 GEMM (mlp1) =================
template <int BUF, int MH, int KH, int VM, typename STF>
__device__ __forceinline__ void gphase(const char* aP0, const char* aP1,
                                       const char* bP0, const char* bP1,
                                       s16x8* bk, f32x4 (&acc)[8][4], STF&& stage) {
  const char* aP = BUF ? aP1 : aP0;
  const char* bP = BUF ? bP1 : bP0;
  s16x8 af[4];
  if (MH == 0) {
#pragma unroll
    for (int ni = 0; ni < 4; ++ni)
      bk[ni] = *(const s16x8*)(bP + KH * 16384 + ni * 1024);
  }
#pragma unroll
  for (int mi = 0; mi < 4; ++mi)
    af[mi] = *(const s16x8*)(aP + KH * 16384 + MH * 4096 + mi * 1024);
  stage();
  if (VM == 10) asm volatile("s_waitcnt vmcnt(10)");
  if (VM == 4) asm volatile("s_waitcnt vmcnt(4)");
  if (VM == 0) asm volatile("s_waitcnt vmcnt(0)");
  __builtin_amdgcn_s_barrier();
  asm volatile("s_waitcnt lgkmcnt(0)");
  __builtin_amdgcn_s_setprio(1);
#pragma unroll
  for (int mi = 0; mi < 4; ++mi)
#pragma unroll
    for (int ni = 0; ni < 4; ++ni)
      acc[MH * 4 + mi][ni] =
          __builtin_amdgcn_mfma_f32_16x16x32_bf16(af[mi], bk[ni], acc[MH * 4 + mi][ni], 0, 0, 0);
  __builtin_amdgcn_s_setprio(0);
  __builtin_amdgcn_s_barrier();
}

template <int EPI>
__device__ __forceinline__ void gemm8_body(
    const unsigned short* __restrict__ A, const unsigned short* __restrict__ Bt,
    void* __restrict__ outp, const float* __restrict__ bias,
    const void* __restrict__ resid, int M, int N, int K, int ntn) {
  __shared__ unsigned short lds[65536];  // 128 KiB
  const char* ldsb = (const char*)lds;
  int tid = threadIdx.x;
  int lane = tid & 63, w = tid >> 6;
  int wm = w >> 2, wn = w & 3;
  int fr = lane & 15, q = lane >> 4;

  int nwg = gridDim.x, orig = blockIdx.x;
  int qd = nwg >> 3, r8 = nwg & 7, xcd = orig & 7, loc = orig >> 3;
  int bid = (xcd < r8 ? xcd * (qd + 1) : r8 * (qd + 1) + (xcd - r8) * qd) + loc;
  int m0 = (bid / ntn) * 256, n0 = (bid % ntn) * 256;

  int rdoff = (q * 16) ^ (((fr >> 1) & 3) << 4);
  const char* aP0 = ldsb + (wm * 128 + fr) * 64 + rdoff;
  const char* aP1 = aP0 + 65536;
  const char* bP0 = ldsb + 32768 + (wn * 64 + fr) * 64 + rdoff;
  const char* bP1 = bP0 + 65536;

  int srow = tid >> 2;
  int seoff = (((tid & 3) ^ ((srow >> 1) & 3))) << 3;
  const char* Ab = (const char*)A + ((size_t)(m0 + srow) * K + seoff) * 2;
  const char* Bb = (const char*)Bt + ((size_t)(n0 + srow) * K + seoff) * 2;
  size_t rstep = (size_t)K * 256;

  auto stg = [&](int mat, int kh, int buf, int tile) {
    const char* gp = (mat ? Bb : Ab) + tile * 128 + kh * 64;
    unsigned short* lp = lds + buf * 32768 + mat * 16384 + kh * 8192 + w * 512;
    gload16((const unsigned short*)gp, lp);
    gload16((const unsigned short*)(gp + rstep), lp + 4096);
  };
  auto nop = [&] {};

  f32x4 acc[8][4] = {};
  s16x8 bk[4];
  int NT = K / 64;

  stg(1, 0, 0, 0);
  stg(0, 0, 0, 0);
  stg(1, 1, 0, 0);
  stg(0, 1, 0, 0);
  stg(1, 0, 1, 1);
  stg(0, 0, 1, 1);
  stg(1, 1, 1, 1);
  asm volatile("s_waitcnt vmcnt(6)");
  __builtin_amdgcn_s_barrier();

  for (int t = 0; t + 3 < NT; t += 2) {
    gphase<0, 0, 0, -1>(aP0, aP1, bP0, bP1, bk, acc, [&] { stg(0, 1, 1, t + 1); });
    gphase<0, 1, 0, 10>(aP0, aP1, bP0, bP1, bk, acc, [&] { stg(1, 0, 0, t + 2); });
    gphase<0, 0, 1, -1>(aP0, aP1, bP0, bP1, bk, acc, [&] { stg(0, 0, 0, t + 2); });
    gphase<0, 1, 1, 10>(aP0, aP1, bP0, bP1, bk, acc, [&] { stg(1, 1, 0, t + 2); });
    gphase<1, 0, 0, -1>(aP0, aP1, bP0, bP1, bk, acc, [&] { stg(0, 1, 0, t + 2); });
    gphase<1, 1, 0, 10>(aP0, aP1, bP0, bP1, bk, acc, [&] { stg(1, 0, 1, t + 3); });
    gphase<1, 0, 1, -1>(aP0, aP1, bP0, bP1, bk, acc, [&] { stg(0, 0, 1, t + 3); });
    gphase<1, 1, 1, 10>(aP0, aP1, bP0, bP1, bk, acc, [&] { stg(1, 1, 1, t + 3); });
  }
  gphase<0, 0, 0, -1>(aP0, aP1, bP0, bP1, bk, acc, [&] { stg(0, 1, 1, NT - 1); });
  gphase<0, 1, 0, -1>(aP0, aP1, bP0, bP1, bk, acc, nop);
  gphase<0, 0, 1, -1>(aP0, aP1, bP0, bP1, bk, acc, nop);
  gphase<0, 1, 1, 4>(aP0, aP1, bP0, bP1, bk, acc, nop);
  gphase<1, 0, 0, -1>(aP0, aP1, bP0, bP1, bk, acc, nop);
  gphase<1, 1, 0, 0>(aP0, aP1, bP0, bP1, bk, acc, nop);
  gphase<1, 0, 1, -1>(aP0, aP1, bP0, bP1, bk, acc, nop);
  gphase<1, 1, 1, -1>(aP0, aP1, bP0, bP1, bk, acc, nop);

#pragma unroll
  for (int am = 0; am < 8; ++am)
#pragma unroll
    for (int ni = 0; ni < 4; ++ni)
#pragma unroll
      for (int rr = 0; rr < 4; ++rr) {
        int row = m0 + wm * 128 + am * 16 + (lane >> 4) * 4 + rr;
        int col = n0 + wn * 64 + ni * 16 + fr;
        size_t idx = (size_t)row * N + col;
        epi_store(EPI, outp, idx, epi_apply(EPI, acc[am][ni][rr], col, idx, bias, resid));
      }
}

// ================= 8-phase 256x192 GEMM (fill path: qkv, proj, mlp2) =================
template <int BUF, int MH, int KH, int VM, typename STF>
__device__ __forceinline__ void gph192(const char* aB0, const char* bKH0, const char* bKH1,
                                       s16x8 (&bk)[3], f32x4 (&acc)[8][3], STF&& stage) {
  const char* aP = aB0 + BUF * 32768 + KH * 16384 + MH * 4096;
  s16x8 af[4];
  if (MH == 0) {
    const char* bp = (KH ? bKH1 : bKH0) + BUF * 24576;
#pragma unroll
    for (int ni = 0; ni < 3; ++ni) bk[ni] = *(const s16x8*)(bp + ni * 2048);
  }
#pragma unroll
  for (int mi = 0; mi < 4; ++mi) af[mi] = *(const s16x8*)(aP + mi * 1024);
  stage();
  if (VM == 2) asm volatile("s_waitcnt vmcnt(2)");
  if (VM == 0) asm volatile("s_waitcnt vmcnt(0)");
  __builtin_amdgcn_s_barrier();
  asm volatile("s_waitcnt lgkmcnt(0)");
  __builtin_amdgcn_s_setprio(1);
#pragma unroll
  for (int mi = 0; mi < 4; ++mi)
#pragma unroll
    for (int ni = 0; ni < 3; ++ni)
      acc[MH * 4 + mi][ni] =
          __builtin_amdgcn_mfma_f32_16x16x32_bf16(af[mi], bk[ni], acc[MH * 4 + mi][ni], 0, 0, 0);
  __builtin_amdgcn_s_setprio(0);
  __builtin_amdgcn_s_barrier();
}

template <int EPI>
__device__ __forceinline__ void gemm192_body(
    const unsigned short* __restrict__ A, const unsigned short* __restrict__ Bt,
    void* __restrict__ outp, const float* __restrict__ bias,
    const void* __restrict__ resid, int M, int N, int K, int ntn) {
  __shared__ char ldsc[114688];  // 112 KiB
  int tid = threadIdx.x;
  int lane = tid & 63, w = tid >> 6;
  int wm = w >> 2, wn = w & 3;
  int fr = lane & 15, q = lane >> 4;

  int nwg = gridDim.x, orig = blockIdx.x;
  int qd = nwg >> 3, r8 = nwg & 7, xcd = orig & 7, loc = orig >> 3;
  int bid = (xcd < r8 ? xcd * (qd + 1) : r8 * (qd + 1) + (xcd - r8) * qd) + loc;
  int m0 = (bid / ntn) * 256, n0 = (bid % ntn) * 192;

  int rdoffA = (q * 16) ^ (((fr >> 1) & 3) << 4);
  const char* aB0 = ldsc + (wm * 128 + fr) * 64 + rdoffA;
  int brow0 = wn * 48 + fr;
  int bsw = brow0 & 7;
  const char* bBase = ldsc + 65536 + brow0 * 128 + (q ^ (bsw & 3)) * 16;
  const char* bKH0 = bBase + ((0 ^ (bsw >> 2)) * 64);
  const char* bKH1 = bBase + ((1 ^ (bsw >> 2)) * 64);

  int srow = tid >> 2;
  int seoffA = (((tid & 3) ^ ((srow >> 1) & 3))) << 3;
  const char* Ab = (const char*)A + ((size_t)(m0 + srow) * K + seoffA) * 2;
  size_t rstep = (size_t)K * 256;
  auto stgA = [&](int kh, int buf, int tile) {
    const char* gp = Ab + tile * 128 + kh * 64;
    unsigned short* lp = (unsigned short*)(ldsc + buf * 32768 + kh * 16384 + w * 1024);
    gload16((const unsigned short*)gp, lp);
    gload16((const unsigned short*)(gp + rstep), (unsigned short*)((char*)lp + 8192));
  };
  const char* Bb2 = (const char*)Bt +
                    ((size_t)(n0 + (tid >> 3)) * K + (((tid & 7) ^ ((tid >> 3) & 7)) * 8)) * 2;
  auto stgB = [&](int j, int buf, int tile) {
    gload16((const unsigned short*)(Bb2 + (size_t)j * 128 * K + tile * 128),
            (unsigned short*)(ldsc + 65536 + buf * 24576 + j * 8192 + w * 1024));
  };
  auto nop = [&] {};

  f32x4 acc[8][3] = {};
  s16x8 bk[3];
  int NT = K / 64;

  stgA(0, 0, 0);
  stgA(1, 0, 0);
  stgB(0, 0, 0);
  stgB(1, 0, 0);
  stgB(2, 0, 0);
  stgA(0, 1, 1);
  asm volatile("s_waitcnt vmcnt(2)");
  __builtin_amdgcn_s_barrier();

  for (int t = 0; t + 3 < NT; t += 2) {
    gph192<0, 0, 0, -1>(aB0, bKH0, bKH1, bk, acc,
                        [&] { stgA(1, 1, t + 1); stgB(0, 1, t + 1); stgB(1, 1, t + 1); });
    gph192<0, 1, 0, -1>(aB0, bKH0, bKH1, bk, acc, [&] { stgB(2, 1, t + 1); });
    gph192<0, 0, 1, -1>(aB0, bKH0, bKH1, bk, acc, [&] { stgA(0, 0, t + 2); });
    gph192<0, 1, 1, 2>(aB0, bKH0, bKH1, bk, acc, nop);
    gph192<1, 0, 0, -1>(aB0, bKH0, bKH1, bk, acc,
                        [&] { stgA(1, 0, t + 2); stgB(0, 0, t + 2); stgB(1, 0, t + 2); });
    gph192<1, 1, 0, -1>(aB0, bKH0, bKH1, bk, acc, [&] { stgB(2, 0, t + 2); });
    gph192<1, 0, 1, -1>(aB0, bKH0, bKH1, bk, acc, [&] { stgA(0, 1, t + 3); });
    gph192<1, 1, 1, 2>(aB0, bKH0, bKH1, bk, acc, nop);
  }
  gph192<0, 0, 0, -1>(aB0, bKH0, bKH1, bk, acc,
                      [&] { stgA(1, 1, NT - 1); stgB(0, 1, NT - 1); stgB(1, 1, NT - 1); });
  gph192<0, 1, 0, -1>(aB0, bKH0, bKH1, bk, acc, [&] { stgB(2, 1, NT - 1); });
  gph192<0, 0, 1, -1>(aB0, bKH0, bKH1, bk, acc, nop);
  gph192<0, 1, 1, 0>(aB0, bKH0, bKH1, bk, acc, nop);
  gph192<1, 0, 0, -1>(aB0, bKH0, bKH1, bk, acc, nop);
  gph192<1, 1, 0, -1>(aB0, bKH0, bKH1, bk, acc, nop);
  gph192<1, 0, 1, -1>(aB0, bKH0, bKH1, bk, acc, nop);
  gph192<1, 1, 1, -1>(aB0, bKH0, bKH1, bk, acc, nop);

#pragma unroll
  for (int am = 0; am < 8; ++am)
#pragma unroll
    for (int ni = 0; ni < 3; ++ni)
#pragma unroll
      for (int rr = 0; rr < 4; ++rr) {
        int row = m0 + wm * 128 + am * 16 + q * 4 + rr;
        int col = n0 + wn * 48 + ni * 16 + fr;
        size_t idx = (size_t)row * N + col;
        epi_store(EPI, outp, idx, epi_apply(EPI, acc[am][ni][rr], col, idx, bias, resid));
      }
}

// named wrappers for rocprof attribution
__global__ __launch_bounds__(512, 2) void gemm_qkv(const unsigned short* A,
                                                   const unsigned short* Bt, void* o,
                                                   const float* b, const void* r, int M,
                                                   int N, int K, int ntn) {
  gemm192_body<0>(A, Bt, o, b, r, M, N, K, ntn);
}
__global__ __launch_bounds__(512, 2) void gemm_mlp1(const unsigned short* A,
                                                    const unsigned short* Bt, void* o,
                                                    const float* b, const void* r, int M,
                                                    int N, int K, int ntn) {
  gemm8_body<2>(A, Bt, o, b, r, M, N, K, ntn);
}
__global__ __launch_bounds__(512, 2) void gemm_proj(const unsigned short* A,
                                                    const unsigned short* Bt, void* o,
                                                    const float* b, const void* r, int M,
                                                    int N, int K, int ntn) {
  gemm192_body<3>(A, Bt, o, b, r, M, N, K, ntn);
}
__global__ __launch_bounds__(512, 2) void gemm_mlp2(const unsigned short* A,
                                                    const unsigned short* Bt, void* o,
                                                    const float* b, const void* r, int M,
                                                    int N, int K, int ntn) {
  gemm192_body<4>(A, Bt, o, b, r, M, N, K, ntn);
}

// ---------------- MFMA attention: one wave per (batch, head) ----------------
__global__ __launch_bounds__(256) void attn_mfma_kernel(const unsigned short* __restrict__ qkv,
                                                        const float* __restrict__ scale,
                                                        unsigned short* __restrict__ ao) {
  __shared__ unsigned short Vt[4][64][40];
  __shared__ unsigned short Pl[4][32][32];
  int wid = threadIdx.x >> 6, lane = threadIdx.x & 63;
  int pair = blockIdx.x * 4 + wid;
  int b = pair / HEADS, h = pair % HEADS;
  const unsigned short* base = qkv + (size_t)b * NTOK * QKVN + h * DHEAD;
  const unsigned short* Qp = base;
  const unsigned short* Kp = base + 768;
  const unsigned short* Vp = base + 1536;

  int c = lane & 15, q = lane >> 4;
  int oct = q * 8;

  unsigned short vcol[NTOK];
#pragma unroll
  for (int j = 0; j < NTOK; ++j) vcol[j] = Vp[(size_t)j * QKVN + lane];
#pragma unroll
  for (int j = 0; j < NTOK; ++j) Vt[wid][lane][j] = vcol[j];
  Vt[wid][lane][31] = 0;

  s16x8 kf[2][2] = {{{0}}}, qf[2][2] = {{{0}}};
#pragma unroll
  for (int t = 0; t < 2; ++t) {
    int row = t * 16 + c;
    if (row < NTOK) {
#pragma unroll
      for (int s = 0; s < 2; ++s) {
        kf[t][s] = *(const s16x8*)(Kp + (size_t)row * QKVN + s * 32 + oct);
        qf[t][s] = *(const s16x8*)(Qp + (size_t)row * QKVN + s * 32 + oct);
      }
    }
  }

  f32x4 st[2][2] = {};
#pragma unroll
  for (int jt = 0; jt < 2; ++jt)
#pragma unroll
    for (int it = 0; it < 2; ++it)
#pragma unroll
      for (int s = 0; s < 2; ++s)
        st[jt][it] =
            __builtin_amdgcn_mfma_f32_16x16x32_bf16(kf[jt][s], qf[it][s], st[jt][it], 0, 0, 0);

  float scl = scale[h];
  float p[2][2][4];
#pragma unroll
  for (int it = 0; it < 2; ++it)
#pragma unroll
    for (int jt = 0; jt < 2; ++jt)
#pragma unroll
      for (int r = 0; r < 4; ++r) {
        int j = jt * 16 + 4 * q + r;
        int i = it * 16 + c;
        float v = st[jt][it][r] * scl;
        if (j == 31 || j == i) v = MASK_VAL;
        p[it][jt][r] = v;
      }
#pragma unroll
  for (int it = 0; it < 2; ++it) {
    float m = p[it][0][0];
#pragma unroll
    for (int jt = 0; jt < 2; ++jt)
#pragma unroll
      for (int r = 0; r < 4; ++r) m = fmaxf(m, p[it][jt][r]);
    m = fmaxf(m, __shfl_xor(m, 16));
    m = fmaxf(m, __shfl_xor(m, 32));
    float s = 0.f;
#pragma unroll
    for (int jt = 0; jt < 2; ++jt)
#pragma unroll
      for (int r = 0; r < 4; ++r) {
        float e = __expf(p[it][jt][r] - m);
        p[it][jt][r] = e;
        s += e;
      }
    s += __shfl_xor(s, 16);
    s += __shfl_xor(s, 32);
    float inv = __builtin_amdgcn_rcpf(s);
#pragma unroll
    for (int jt = 0; jt < 2; ++jt)
#pragma unroll
      for (int r = 0; r < 4; ++r) p[it][jt][r] *= inv;
  }
#pragma unroll
  for (int it = 0; it < 2; ++it)
#pragma unroll
    for (int jt = 0; jt < 2; ++jt) {
      unsigned int w0 =
          (unsigned int)f2bs(p[it][jt][0]) | ((unsigned int)f2bs(p[it][jt][1]) << 16);
      unsigned int w1 =
          (unsigned int)f2bs(p[it][jt][2]) | ((unsigned int)f2bs(p[it][jt][3]) << 16);
      uint2 pk = {w0, w1};
      *(uint2*)&Pl[wid][it * 16 + c][jt * 16 + 4 * q] = pk;
    }

  s16x8 pa[2];
#pragma unroll
  for (int it = 0; it < 2; ++it) pa[it] = *(const s16x8*)&Pl[wid][it * 16 + c][oct];
  f32x4 o[2][4];
#pragma unroll
  for (int it = 0; it < 2; ++it)
#pragma unroll
    for (int dt = 0; dt < 4; ++dt) {
      s16x8 vb = *(const s16x8*)&Vt[wid][dt * 16 + c][oct];
      f32x4 z = {0.f, 0.f, 0.f, 0.f};
      o[it][dt] = __builtin_amdgcn_mfma_f32_16x16x32_bf16(pa[it], vb, z, 0, 0, 0);
    }
#pragma unroll
  for (int it = 0; it < 2; ++it)
#pragma unroll
    for (int r = 0; r < 4; ++r) {
      int i = it * 16 + 4 * q + r;
      if (i < NTOK) {
        size_t rowoff = ((size_t)b * NTOK + i) * DIM + h * DHEAD;
#pragma unroll
        for (int dt = 0; dt < 4; ++dt) ao[rowoff + dt * 16 + c] = f2bs(o[it][dt][r]);
      }
    }
}

// ---------------- launcher ----------------
extern "C" void kernel_launch(void* const* d_in, const int* in_sizes, int n_in,
                              void* d_out, int out_size, void* d_ws, size_t ws_size,
                              hipStream_t stream) {
  (void)in_sizes; (void)n_in; (void)out_size; (void)ws_size;
  const float* x = (const float*)d_in[0];
  const float* ln1_g = (const float*)d_in[1];
  const float* ln1_b = (const float*)d_in[2];
  const float* w_qkv = (const float*)d_in[3];
  const float* scale = (const float*)d_in[4];
  const float* w_o = (const float*)d_in[5];
  const float* b_o = (const float*)d_in[6];
  const float* ln2_g = (const float*)d_in[7];
  const float* ln2_b = (const float*)d_in[8];
  const float* w1 = (const float*)d_in[9];
  const float* b1 = (const float*)d_in[10];
  const float* w2 = (const float*)d_in[11];
  const float* b2 = (const float*)d_in[12];

  char* ws = (char*)d_ws;
  unsigned short* buf1 = (unsigned short*)(ws + 0);
  unsigned short* qkv_bf = (unsigned short*)(ws + 24379392);
  unsigned short* x2 = (unsigned short*)(ws + 24379392);  // aliases qkv (qkv dead)
  unsigned short* g_bf = (unsigned short*)(ws + 97517568);
  unsigned short* wqkvT = (unsigned short*)(ws + 195035136);  // [2304][768]
  unsigned short* woT = (unsigned short*)(ws + 198574080);    // [768][768]
  unsigned short* w1T = (unsigned short*)(ws + 199753728);    // [3072][768]
  unsigned short* w2T = (unsigned short*)(ws + 204472320);    // [768][3072]

  transpose_kernel<<<dim3(QKVN / 64, DIM / 64), 256, 0, stream>>>(w_qkv, wqkvT, DIM, QKVN);
  transpose_kernel<<<dim3(DIM / 64, DIM / 64), 256, 0, stream>>>(w_o, woT, DIM, DIM);
  transpose_kernel<<<dim3(HIDDEN / 64, DIM / 64), 256, 0, stream>>>(w1, w1T, DIM, HIDDEN);
  transpose_kernel<<<dim3(DIM / 64, HIDDEN / 64), 256, 0, stream>>>(w2, w2T, HIDDEN, DIM);

  ln_kernel<<<MTOK / 4, 256, 0, stream>>>(x, ln1_g, ln1_b, buf1);
  // qkv GEMM   [256x192 tiles, grid 744 = 62 x 12]
  gemm_qkv<<<(MTOK / 256) * (QKVN / 192), 512, 0, stream>>>(
      buf1, wqkvT, qkv_bf, nullptr, nullptr, MTOK, QKVN, DIM, QKVN / 192);
  attn_mfma_kernel<<<(BATCH * HEADS) / 4, 256, 0, stream>>>(qkv_bf, scale, buf1);
  // proj + residual(x, f32) -> x2 (bf16)   [256x192 tiles, grid 248]
  gemm_proj<<<(MTOK / 256) * (DIM / 192), 512, 0, stream>>>(
      buf1, woT, x2, b_o, x, MTOK, DIM, DIM, DIM / 192);
  ln_bf16_kernel<<<MTOK / 4, 256, 0, stream>>>(x2, ln2_g, ln2_b, buf1);
  // mlp1 + tanh-GELU   [256x256 tiles, grid 744]
  gemm_mlp1<<<(MTOK / 256) * (HIDDEN / 256), 512, 0, stream>>>(
      buf1, w1T, g_bf, b1, nullptr, MTOK, HIDDEN, DIM, HIDDEN / 256);
  // mlp2 + residual(x2, bf16) -> out (f32)   [256x192 tiles, grid 248]
  gemm_mlp2<<<(MTOK / 256) * (DIM / 192), 512, 0, stream>>>(
      g_bf, w2T, (float*)d_out, b2, x2, MTOK, DIM, HIDDEN, DIM / 192);
}